// Round 17
// baseline (153.155 us; speedup 1.0000x reference)
//
#include <hip/hip_runtime.h>
#include <hip/hip_bf16.h>
#include <stdint.h>

// Problem constants (from reference)
#define NB 8
#define NT 2048
#define ND 512
#define NH 4
#define NDK 128
#define KW 11

typedef unsigned short u16;
typedef __attribute__((ext_vector_type(4))) float f32x4;
typedef __attribute__((ext_vector_type(16))) float f32x16;
typedef __attribute__((ext_vector_type(4))) float fv4;
typedef __attribute__((ext_vector_type(8))) short s16x8;   // 8 bf16 = 4 VGPR
typedef __attribute__((ext_vector_type(4))) unsigned short u16x4;
typedef __attribute__((ext_vector_type(4))) int i32x4;

#define AS1 __attribute__((address_space(1)))
#define AS3 __attribute__((address_space(3)))

__device__ __forceinline__ u16 f2bf(float f){
  unsigned u = __float_as_uint(f);
  u += 0x7fffu + ((u >> 16) & 1u);      // RNE
  return (u16)(u >> 16);
}
__device__ __forceinline__ float bf2f(u16 h){ return __uint_as_float(((unsigned)h) << 16); }
__device__ __forceinline__ unsigned pack2bf(float a, float b){
  float2 t; t.x = a; t.y = b;
  __hip_bfloat162 h = __float22bfloat162_rn(t);
  return *reinterpret_cast<unsigned*>(&h);
}

// ---------------------------------------------------------------- fused prep:
// blocks [0,1024): x -> bf16 (grid-stride)
// blocks [1024,1792): Wqkv transpose+cvt; [1792,2048): Wout transpose+cvt
// blocks [2048,2056): per-batch mask scan -> idx list (128-padded), pos16 map, count
__device__ __forceinline__ void transpose_body(
    const float* __restrict__ in, u16* __restrict__ out, int R, int C,
    int bx, int by, int tid)
{
  __shared__ float tile[32][33];
  const int cb = bx * 32, rb = by * 32;
  const int tx = tid & 31, ty = tid >> 5;   // (32,8)
  #pragma unroll
  for (int i = 0; i < 4; ++i)
    tile[ty + i*8][tx] = in[(size_t)(rb + ty + i*8) * C + cb + tx];
  __syncthreads();
  #pragma unroll
  for (int i = 0; i < 4; ++i)
    out[(size_t)(cb + ty + i*8) * R + rb + tx] = f2bf(tile[tx][ty + i*8]);
}

__global__ void prep_kernel(const float* __restrict__ x, u16* __restrict__ xb,
                            const float* __restrict__ Wqkv, u16* __restrict__ wqkvT,
                            const float* __restrict__ Wout, u16* __restrict__ woutT,
                            const float* __restrict__ mask, u16* __restrict__ idxb,
                            u16* __restrict__ pos16, int* __restrict__ cntb)
{
  const int bid = blockIdx.x, tid = threadIdx.x;
  if (bid < 1024){
    const int n4 = (NB*NT*ND)/4;
    for (int i = bid*256 + tid; i < n4; i += 1024*256){
      float4 v = reinterpret_cast<const float4*>(x)[i];
      u16x4 o = { f2bf(v.x), f2bf(v.y), f2bf(v.z), f2bf(v.w) };
      reinterpret_cast<u16x4*>(xb)[i] = o;
    }
  } else if (bid < 1792){
    const int idx = bid - 1024;              // grid (48,16)
    transpose_body(Wqkv, wqkvT, 512, 1536, idx % 48, idx / 48, tid);
  } else if (bid < 2048){
    const int idx = bid - 1792;              // grid (16,16)
    transpose_body(Wout, woutT, 512, 512, idx % 16, idx / 16, tid);
  } else {
    // per-batch mask scan: ascending valid-key list (128-padded with 0), pos16 map
    const int b = bid - 2048;
    __shared__ int s[256];
    const float* mb = mask + (size_t)b * NT;
    float4 a = *reinterpret_cast<const float4*>(&mb[tid*8]);
    float4 c4 = *reinterpret_cast<const float4*>(&mb[tid*8 + 4]);
    float vals[8] = {a.x, a.y, a.z, a.w, c4.x, c4.y, c4.z, c4.w};
    int lc = 0;
    #pragma unroll
    for (int j = 0; j < 8; ++j) lc += (vals[j] != 0.f);
    s[tid] = lc; __syncthreads();
    #pragma unroll
    for (int d = 1; d < 256; d <<= 1){
      const int v = (tid >= d) ? s[tid - d] : 0;
      __syncthreads();
      s[tid] += v;
      __syncthreads();
    }
    const int excl = s[tid] - lc;
    const int total = s[255];
    u16* ib = idxb + (size_t)b * NT;
    u16* pb = pos16 + (size_t)b * NT;
    int off = excl;
    #pragma unroll
    for (int j = 0; j < 8; ++j){
      const int t = tid*8 + j;
      if (vals[j] != 0.f){ ib[off] = (u16)t; pb[t] = (u16)off; ++off; }
      else pb[t] = (u16)0xFFFF;
    }
    const int padded = (total + 127) & ~127;
    for (int j = total + tid; j < padded; j += 256) ib[j] = 0;
    if (tid == 0) cntb[b] = total;
  }
}

// ---------------------------------------------------------------- Q GEMM (all rows)
// BK=64 + XOR swizzle (rule #21, verified R13). C -> bf16 qb (stride 512).
__global__ __launch_bounds__(256, 2) void gemm_q(
    const u16* __restrict__ A, const u16* __restrict__ Bt, const float* __restrict__ bias,
    u16* __restrict__ Cb, int M, int N, int Kd)
{
  __shared__ u16 As[128 * 64];
  __shared__ u16 Bs[128 * 64];
  const int tid = threadIdx.x;
  const int m0 = blockIdx.y * 128, n0 = blockIdx.x * 128;
  const int w = tid >> 6, l = tid & 63, wr = w >> 1, wc = w & 1;
  const int r15 = l & 15, g = l >> 4;

  f32x4 acc[4][4] = {};

  const int r0 = tid >> 3;
  const int scol8 = ((tid & 7) ^ (r0 & 7)) << 3;
  const u16* Ag = A  + (size_t)(m0 + r0) * Kd + scol8;
  const u16* Bg = Bt + (size_t)(n0 + r0) * Kd + scol8;
  u16* Al = &As[(size_t)tid * 8];
  u16* Bl = &Bs[(size_t)tid * 8];

  for (int k0 = 0; k0 < Kd; k0 += 64){
    #pragma unroll
    for (int i = 0; i < 4; ++i)
      __builtin_amdgcn_global_load_lds((AS1 void*)(Ag + (size_t)(i*32) * Kd + k0),
                                       (AS3 void*)(Al + i*2048), 16, 0, 0);
    #pragma unroll
    for (int i = 0; i < 4; ++i)
      __builtin_amdgcn_global_load_lds((AS1 void*)(Bg + (size_t)(i*32) * Kd + k0),
                                       (AS3 void*)(Bl + i*2048), 16, 0, 0);
    __syncthreads();
    #pragma unroll
    for (int kk = 0; kk < 2; ++kk){
      s16x8 af[4], bfr[4];
      #pragma unroll
      for (int m = 0; m < 4; ++m){
        const int R = wr*64 + m*16 + r15;
        af[m] = *reinterpret_cast<const s16x8*>(&As[R*64 + (((kk*4 + g) ^ (r15 & 7)) << 3)]);
      }
      #pragma unroll
      for (int n = 0; n < 4; ++n){
        const int R = wc*64 + n*16 + r15;
        bfr[n] = *reinterpret_cast<const s16x8*>(&Bs[R*64 + (((kk*4 + g) ^ (r15 & 7)) << 3)]);
      }
      #pragma unroll
      for (int m = 0; m < 4; ++m){
        #pragma unroll
        for (int n = 0; n < 4; ++n)
          acc[m][n] = __builtin_amdgcn_mfma_f32_16x16x32_bf16(af[m], bfr[n], acc[m][n], 0, 0, 0);
      }
    }
    __syncthreads();
  }

  #pragma unroll
  for (int m = 0; m < 4; ++m){
    const int gr0 = m0 + wr*64 + m*16 + g*4;
    #pragma unroll
    for (int n = 0; n < 4; ++n){
      const int gc = n0 + wc*64 + n*16 + r15;
      const float bv = bias[gc];
      #pragma unroll
      for (int j = 0; j < 4; ++j)
        Cb[(size_t)(gr0 + j) * N + gc] = f2bf(acc[m][n][j] + bv);
    }
  }
}

// ---------------------------------------------------------------- K/V GEMM on COMPACTED rows
// A rows gathered via idx (per-lane global_load_lds source). Output row == compact pos.
// Epilogue writes kcb[bh][pos][128] (K cols) and subtiled vtc (V cols) directly.
__global__ __launch_bounds__(256, 2) void gemm_kv(
    const u16* __restrict__ xb, const u16* __restrict__ Bt, const float* __restrict__ bias,
    const u16* __restrict__ idxb, const int* __restrict__ cntb,
    u16* __restrict__ kcb, u16* __restrict__ vtc)
{
  const int b = blockIdx.y >> 4, mb = blockIdx.y & 15;
  const int total = cntb[b];
  const int padded = (total + 127) & ~127;
  const int m0 = mb * 128;
  if (m0 >= padded) return;
  const int Kd = ND, n0 = blockIdx.x * 128;

  __shared__ u16 As[128 * 64];
  __shared__ u16 Bs[128 * 64];
  const int tid = threadIdx.x;
  const int w = tid >> 6, l = tid & 63, wr = w >> 1, wc = w & 1;
  const int r15 = l & 15, g = l >> 4;

  f32x4 acc[4][4] = {};

  const int r0 = tid >> 3;
  const int scol8 = ((tid & 7) ^ (r0 & 7)) << 3;
  const u16* ib = idxb + (size_t)b * NT;
  const u16* Ab = xb + (size_t)b * NT * ND;
  const u16* Ag0 = Ab + (size_t)ib[m0 + r0      ] * Kd + scol8;
  const u16* Ag1 = Ab + (size_t)ib[m0 + r0 + 32 ] * Kd + scol8;
  const u16* Ag2 = Ab + (size_t)ib[m0 + r0 + 64 ] * Kd + scol8;
  const u16* Ag3 = Ab + (size_t)ib[m0 + r0 + 96 ] * Kd + scol8;
  const u16* Bg = Bt + (size_t)(n0 + r0) * Kd + scol8;
  u16* Al = &As[(size_t)tid * 8];
  u16* Bl = &Bs[(size_t)tid * 8];

  for (int k0 = 0; k0 < Kd; k0 += 64){
    __builtin_amdgcn_global_load_lds((AS1 void*)(Ag0 + k0), (AS3 void*)(Al        ), 16, 0, 0);
    __builtin_amdgcn_global_load_lds((AS1 void*)(Ag1 + k0), (AS3 void*)(Al + 2048 ), 16, 0, 0);
    __builtin_amdgcn_global_load_lds((AS1 void*)(Ag2 + k0), (AS3 void*)(Al + 4096 ), 16, 0, 0);
    __builtin_amdgcn_global_load_lds((AS1 void*)(Ag3 + k0), (AS3 void*)(Al + 6144 ), 16, 0, 0);
    #pragma unroll
    for (int i = 0; i < 4; ++i)
      __builtin_amdgcn_global_load_lds((AS1 void*)(Bg + (size_t)(i*32) * Kd + k0),
                                       (AS3 void*)(Bl + i*2048), 16, 0, 0);
    __syncthreads();
    #pragma unroll
    for (int kk = 0; kk < 2; ++kk){
      s16x8 af[4], bfr[4];
      #pragma unroll
      for (int m = 0; m < 4; ++m){
        const int R = wr*64 + m*16 + r15;
        af[m] = *reinterpret_cast<const s16x8*>(&As[R*64 + (((kk*4 + g) ^ (r15 & 7)) << 3)]);
      }
      #pragma unroll
      for (int n = 0; n < 4; ++n){
        const int R = wc*64 + n*16 + r15;
        bfr[n] = *reinterpret_cast<const s16x8*>(&Bs[R*64 + (((kk*4 + g) ^ (r15 & 7)) << 3)]);
      }
      #pragma unroll
      for (int m = 0; m < 4; ++m){
        #pragma unroll
        for (int n = 0; n < 4; ++n)
          acc[m][n] = __builtin_amdgcn_mfma_f32_16x16x32_bf16(af[m], bfr[n], acc[m][n], 0, 0, 0);
      }
    }
    __syncthreads();
  }

  const bool isK = (n0 < 512);                  // block-uniform (128-aligned split)
  #pragma unroll
  for (int m = 0; m < 4; ++m){
    const int gr0 = m0 + wr*64 + m*16 + g*4;    // compact position base
    #pragma unroll
    for (int n = 0; n < 4; ++n){
      const int gc = n0 + wc*64 + n*16 + r15;   // 0..1023 (K cols then V cols)
      const float bv = bias[gc];
      const int d = isK ? gc : (gc - 512);
      const int bh = b*4 + (d >> 7), dk = d & 127;
      #pragma unroll
      for (int j = 0; j < 4; ++j){
        const u16 hv = f2bf(acc[m][n][j] + bv);
        const int pos = gr0 + j;
        if (isK){
          kcb[((size_t)bh*NT + pos)*NDK + dk] = hv;
        } else {
          vtc[((size_t)bh*32 + (pos >> 6))*8192 + ((pos & 63) >> 3)*1024 + dk*8 + (pos & 7)] = hv;
        }
      }
    }
  }
}

// ---------------------------------------------------------------- out GEMM + fused FSMN
// BK=64 + XOR swizzle. FSMN taps read compacted V (vtc) via pos16 map (0xFFFF = masked);
// mask multiplies are replaced by validity selects (mask is exactly {0,1}).
__global__ __launch_bounds__(256, 2) void gemm_out(
    const u16* __restrict__ A, const u16* __restrict__ Bt, const float* __restrict__ bias,
    float* __restrict__ Cf, const u16* __restrict__ pos16, const u16* __restrict__ vtc,
    const float* __restrict__ fsmn_w, int M, int N, int Kd)
{
  __shared__ u16 As[128 * 64];
  __shared__ u16 Bs[128 * 64];
  const int tid = threadIdx.x;
  const int m0 = blockIdx.y * 128, n0 = blockIdx.x * 128;
  const int w = tid >> 6, l = tid & 63, wr = w >> 1, wc = w & 1;
  const int r15 = l & 15, g = l >> 4;

  f32x4 acc[4][4] = {};

  const int r0 = tid >> 3;
  const int scol8 = ((tid & 7) ^ (r0 & 7)) << 3;
  const u16* Ag = A  + (size_t)(m0 + r0) * Kd + scol8;
  const u16* Bg = Bt + (size_t)(n0 + r0) * Kd + scol8;
  u16* Al = &As[(size_t)tid * 8];
  u16* Bl = &Bs[(size_t)tid * 8];

  for (int k0 = 0; k0 < Kd; k0 += 64){
    #pragma unroll
    for (int i = 0; i < 4; ++i)
      __builtin_amdgcn_global_load_lds((AS1 void*)(Ag + (size_t)(i*32) * Kd + k0),
                                       (AS3 void*)(Al + i*2048), 16, 0, 0);
    #pragma unroll
    for (int i = 0; i < 4; ++i)
      __builtin_amdgcn_global_load_lds((AS1 void*)(Bg + (size_t)(i*32) * Kd + k0),
                                       (AS3 void*)(Bl + i*2048), 16, 0, 0);
    __syncthreads();
    #pragma unroll
    for (int kk = 0; kk < 2; ++kk){
      s16x8 af[4], bfr[4];
      #pragma unroll
      for (int m = 0; m < 4; ++m){
        const int R = wr*64 + m*16 + r15;
        af[m] = *reinterpret_cast<const s16x8*>(&As[R*64 + (((kk*4 + g) ^ (r15 & 7)) << 3)]);
      }
      #pragma unroll
      for (int n = 0; n < 4; ++n){
        const int R = wc*64 + n*16 + r15;
        bfr[n] = *reinterpret_cast<const s16x8*>(&Bs[R*64 + (((kk*4 + g) ^ (r15 & 7)) << 3)]);
      }
      #pragma unroll
      for (int m = 0; m < 4; ++m){
        #pragma unroll
        for (int n = 0; n < 4; ++n)
          acc[m][n] = __builtin_amdgcn_mfma_f32_16x16x32_bf16(af[m], bfr[n], acc[m][n], 0, 0, 0);
      }
    }
    __syncthreads();
  }

  float wv[4][KW];
  #pragma unroll
  for (int n = 0; n < 4; ++n){
    const int gc = n0 + wc*64 + n*16 + r15;
    #pragma unroll
    for (int i = 0; i < KW; ++i) wv[n][i] = fsmn_w[gc*KW + i];
  }
  #pragma unroll
  for (int m = 0; m < 4; ++m){
    const int gr0 = m0 + wr*64 + m*16 + g*4;
    const int bb = gr0 >> 11, t0 = gr0 & 2047;
    const u16* pb = pos16 + (size_t)bb * NT;
    int tap[14];
    #pragma unroll
    for (int i = 0; i < 14; ++i){
      const int tau = t0 - 5 + i;
      tap[i] = ((unsigned)tau < (unsigned)NT) ? (int)pb[tau] : 0xFFFF;
    }
    #pragma unroll
    for (int n = 0; n < 4; ++n){
      const int gc = n0 + wc*64 + n*16 + r15;
      const float bv = bias[gc];
      const int hh = gc >> 7, dk = gc & 127;
      const u16* vtb = vtc + ((size_t)(bb*4 + hh)*32)*8192 + dk*8;
      float vmv[14];
      #pragma unroll
      for (int i = 0; i < 14; ++i){
        const int p = tap[i];
        const int pc = (p == 0xFFFF) ? 0 : p;
        const float v = bf2f(vtb[(pc >> 6)*8192 + ((pc & 63) >> 3)*1024 + (pc & 7)]);
        vmv[i] = (p == 0xFFFF) ? 0.f : v;
      }
      #pragma unroll
      for (int j = 0; j < 4; ++j){
        float conv = vmv[5 + j];                    // vm[t] residual term
        #pragma unroll
        for (int i = 0; i < KW; ++i) conv = fmaf(wv[n][i], vmv[j + i], conv);
        const float fs = (tap[5 + j] != 0xFFFF) ? conv : 0.f;
        Cf[(size_t)(gr0 + j) * N + gc] = acc[m][n][j] + bv + fs;
      }
    }
  }
}

// ---------------------------------------------------------------- flash attention, COMPACTED KEYS
// R16 structure (verified 63us): ntiles = ceil(cnt/64) runtime; last tile kidx<cnt
// predicate; no mask in inner loop. K rows 256B compact; V subtiled (conflict-free).
// Q now from qb (stride 512). DO NOT raise launch_bounds 2nd arg (R9 spill lesson).
#define ATT_MFMA(a, bb, c) __builtin_amdgcn_mfma_f32_32x32x16_bf16(a, bb, c, 0, 0, 0)
#define C1F 0.12751741567f   /* (1/sqrt(128)) * log2(e) */

__global__ __launch_bounds__(256, 2) void attn_kernel(
    const u16* __restrict__ qb, const u16* __restrict__ kcb,
    const u16* __restrict__ vtc, const int* __restrict__ cntb,
    u16* __restrict__ ctxb)
{
  __shared__ u16 Ks[2][64 * 128];   // [key][dk], swizzled 16B chunks
  __shared__ u16 Vs[2][8 * 128 * 8];// [kg][dk][8 keys] subtiled (linear image of vtc tile)
  const int tid = threadIdx.x;
  const int w = tid >> 6, l = tid & 63, l31 = l & 31, hi = l >> 5;

  // XCD-bijective remap: all 16 q-blocks of one bh land on one XCD (K/V L2 locality)
  const int lin = blockIdx.x + blockIdx.y * 8;    // grid = (8, 64)
  const int xcd = lin & 7, jj = lin >> 3;         // jj 0..63
  const int bh = xcd * 4 + (jj & 3), qblk = jj >> 2;
  const int b = bh >> 2, h = bh & 3;
  const int q0 = qblk * 128;

  const u16* kb   = kcb + (size_t)bh * NT * NDK;
  const u16* vtb  = vtc + (size_t)bh * 32 * 8192;
  const int total = cntb[b];
  const int ntiles = (total + 63) >> 6;

  // Q in registers (B-operand): lane holds Q[q0+w*32+l31][s*16 + hi*8 .. +7]
  s16x8 qf[8];
  {
    const u16* qrow = qb + (size_t)(b*NT + q0 + w*32 + l31) * ND + h * NDK;
    #pragma unroll
    for (int s = 0; s < 8; ++s)
      qf[s] = *reinterpret_cast<const s16x8*>(qrow + s*16 + hi*8);
  }

  float mrun = -1e30f, lrun = 0.f;
  f32x16 o0 = {}, o1 = {}, o2 = {}, o3 = {};

#define STAGE(buf, kvo) do { \
    _Pragma("unroll") \
    for (int i_ = 0; i_ < 4; ++i_){ \
      const int n_ = i_*256 + tid, kr_ = n_ >> 4, c_ = n_ & 15; \
      const u16* gp_ = kb + (size_t)((kvo) + kr_) * NDK + ((c_ ^ (kr_ & 7)) << 3); \
      __builtin_amdgcn_global_load_lds((AS1 void*)gp_, (AS3 void*)&Ks[buf][n_*8], 16, 0, 0); \
    } \
    const u16* vsrc_ = vtb + ((kvo) >> 6) * 8192; \
    _Pragma("unroll") \
    for (int i_ = 0; i_ < 4; ++i_){ \
      const int n_ = i_*256 + tid; \
      __builtin_amdgcn_global_load_lds((AS1 void*)(vsrc_ + n_*8), \
                                       (AS3 void*)&Vs[buf][n_*8], 16, 0, 0); \
    } \
  } while(0)

  if (ntiles > 0) STAGE(0, 0);
  __syncthreads();
  int cur = 0;

  for (int t = 0; t < ntiles; ++t){
    const int kv0 = t * 64;
    if (t + 1 < ntiles) STAGE(cur ^ 1, kv0 + 64);

    // S^T = K Q^T: d0 keys kv0+0..31, d1 keys kv0+32..63; lane owns q-col l31
    f32x16 d0 = {}, d1 = {};
    __builtin_amdgcn_s_setprio(1);
    #pragma unroll
    for (int s = 0; s < 8; ++s){
      const int cg = s*2 + hi;
      s16x8 kf0 = *reinterpret_cast<const s16x8*>(
          &Ks[cur][ l31*128      + ((cg ^ (l31 & 7)) << 3) ]);
      s16x8 kf1 = *reinterpret_cast<const s16x8*>(
          &Ks[cur][ (32+l31)*128 + ((cg ^ (l31 & 7)) << 3) ]);
      d0 = ATT_MFMA(kf0, qf[s], d0);
      d1 = ATT_MFMA(kf1, qf[s], d1);
    }
    __builtin_amdgcn_s_setprio(0);

    // row max over raw scores: max3-friendly tree, then cross-half
    float mx0 = fmaxf(d0[0], d0[1]), mx1 = fmaxf(d0[2], d0[3]);
    float mx2 = fmaxf(d1[0], d1[1]), mx3 = fmaxf(d1[2], d1[3]);
    #pragma unroll
    for (int r = 4; r < 16; r += 4){
      mx0 = fmaxf(mx0, fmaxf(d0[r],   d0[r+1]));
      mx1 = fmaxf(mx1, fmaxf(d0[r+2], d0[r+3]));
      mx2 = fmaxf(mx2, fmaxf(d1[r],   d1[r+1]));
      mx3 = fmaxf(mx3, fmaxf(d1[r+2], d1[r+3]));
    }
    float tmx = fmaxf(fmaxf(mx0, mx1), fmaxf(mx2, mx3));
    tmx = fmaxf(tmx, __shfl_xor(tmx, 32));

    // T13 defer-max (raw-score threshold 64 ~ 8 nats)
    if (!__all(tmx <= mrun + 64.f)){
      const float mn = fmaxf(mrun, tmx);
      const float corr = __builtin_amdgcn_exp2f((mrun - mn) * C1F);
      mrun = mn; lrun *= corr;
      #pragma unroll
      for (int r = 0; r < 16; ++r){
        const int qs = (r & 3) + 8*(r >> 2) + 4*hi;
        const float cq = __shfl(corr, qs);
        o0[r] *= cq; o1[r] *= cq; o2[r] *= cq; o3[r] *= cq;
      }
    }

    // p = exp2(fma(s, c1, -m*c1)); no mask (keys pre-compacted); last tile: kidx<cnt
    const float mm = mrun * C1F;
    float ts = 0.f;
    if (t + 1 < ntiles){
      #pragma unroll
      for (int r = 0; r < 16; ++r){
        const float p0 = __builtin_amdgcn_exp2f(fmaf(d0[r], C1F, -mm));
        const float p1 = __builtin_amdgcn_exp2f(fmaf(d1[r], C1F, -mm));
        d0[r] = p0; d1[r] = p1; ts += p0 + p1;
      }
    } else {
      #pragma unroll
      for (int r = 0; r < 16; ++r){
        const int kidx = kv0 + (r >> 2)*8 + 4*hi + (r & 3);
        const float p0 = (kidx      < total) ? __builtin_amdgcn_exp2f(fmaf(d0[r], C1F, -mm)) : 0.f;
        const float p1 = (kidx + 32 < total) ? __builtin_amdgcn_exp2f(fmaf(d1[r], C1F, -mm)) : 0.f;
        d0[r] = p0; d1[r] = p1; ts += p0 + p1;
      }
    }
    ts += __shfl_xor(ts, 32);
    lrun += ts;

    // pack p -> bf16 pairs
    unsigned pku[2][4][2];
    #pragma unroll
    for (int r8 = 0; r8 < 4; ++r8){
      pku[0][r8][0] = pack2bf(d0[4*r8+0], d0[4*r8+1]);
      pku[0][r8][1] = pack2bf(d0[4*r8+2], d0[4*r8+3]);
      pku[1][r8][0] = pack2bf(d1[4*r8+0], d1[4*r8+1]);
      pku[1][r8][1] = pack2bf(d1[4*r8+2], d1[4*r8+3]);
    }

    // PV: per k-step build A-frag with 2 permlane32_swap, then 4 dk-blocks.
    const int vb0 = hi*1024 + l31*8;
    #pragma unroll
    for (int ks = 0; ks < 4; ++ks){
      const int bb = ks >> 1, rlo = (ks & 1) * 2;
      int u0 = (int)pku[bb][rlo][0],   u1 = (int)pku[bb][rlo][1];
      int v0 = (int)pku[bb][rlo+1][0], v1 = (int)pku[bb][rlo+1][1];
      asm("v_permlane32_swap_b32 %0, %1" : "+v"(u0), "+v"(v0));
      asm("v_permlane32_swap_b32 %0, %1" : "+v"(u1), "+v"(v1));
      union { i32x4 i; s16x8 hv; } pu;
      pu.i[0] = u0; pu.i[1] = u1; pu.i[2] = v0; pu.i[3] = v1;
      const int off = ks*2048 + vb0;
      s16x8 vf0 = *reinterpret_cast<const s16x8*>(&Vs[cur][ off       ]);
      s16x8 vf1 = *reinterpret_cast<const s16x8*>(&Vs[cur][ off + 256 ]);
      s16x8 vf2 = *reinterpret_cast<const s16x8*>(&Vs[cur][ off + 512 ]);
      s16x8 vf3 = *reinterpret_cast<const s16x8*>(&Vs[cur][ off + 768 ]);
      __builtin_amdgcn_s_setprio(1);
      o0 = ATT_MFMA(pu.hv, vf0, o0);
      o1 = ATT_MFMA(pu.hv, vf1, o1);
      o2 = ATT_MFMA(pu.hv, vf2, o2);
      o3 = ATT_MFMA(pu.hv, vf3, o3);
      __builtin_amdgcn_s_setprio(0);
    }

    __syncthreads();
    cur ^= 1;
  }

  // epilogue: O[q][dk] regs: col dk = dkblk*32 + l31, row q = (r&3)+8*(r>>2)+4*hi
  #pragma unroll
  for (int r = 0; r < 16; ++r){
    const int qs = (r & 3) + 8*(r >> 2) + 4*hi;
    const float lr = __shfl(lrun, qs);
    const float rl = (lr > 0.f) ? (1.f / lr) : 0.f;
    const int row = q0 + w*32 + qs;
    u16* cp = ctxb + (size_t)(b*NT + row) * ND + h*NDK + l31;
    cp[0]  = f2bf(o0[r] * rl);
    cp[32] = f2bf(o1[r] * rl);
    cp[64] = f2bf(o2[r] * rl);
    cp[96] = f2bf(o3[r] * rl);
  }
#undef STAGE
}

// ---------------------------------------------------------------- launcher
extern "C" void kernel_launch(void* const* d_in, const int* in_sizes, int n_in,
                              void* d_out, int out_size, void* d_ws, size_t ws_size,
                              hipStream_t stream) {
  const float* x      = (const float*)d_in[0];
  const float* mask   = (const float*)d_in[1];
  const float* Wqkv   = (const float*)d_in[2];
  const float* bqkv   = (const float*)d_in[3];
  const float* Wout   = (const float*)d_in[4];
  const float* bout   = (const float*)d_in[5];
  const float* fsmn_w = (const float*)d_in[6];
  float* out = (float*)d_out;

  // workspace layout (bytes), total ~86 MB
  char* ws = (char*)d_ws;
  u16* xb    = (u16*)ws;                         // 16,777,216
  u16* wqkvT = (u16*)(ws + 16777216);            //  1,572,864
  u16* woutT = (u16*)(ws + 18350080);            //    524,288
  u16* qb    = (u16*)(ws + 18874368);            // 16,777,216
  u16* kcb   = (u16*)(ws + 35651584);            // 16,777,216
  u16* vtc   = (u16*)(ws + 52428800);            // 16,777,216
  u16* ctxb  = (u16*)(ws + 69206016);            // 16,777,216
  u16* idxb  = (u16*)(ws + 85983232);            //     32,768
  u16* pos16 = (u16*)(ws + 86016000);            //     32,768
  int* cntb  = (int*)(ws + 86048768);            //         32

  prep_kernel<<<2056, 256, 0, stream>>>(x, xb, Wqkv, wqkvT, Wout, woutT,
                                        mask, idxb, pos16, cntb);
  gemm_q<<<dim3(512/128, 16384/128), 256, 0, stream>>>(
      xb, wqkvT, bqkv, qb, NB*NT, ND, ND);
  gemm_kv<<<dim3(1024/128, 128), 256, 0, stream>>>(
      xb, wqkvT + 512*512, bqkv + 512, idxb, cntb, kcb, vtc);
  attn_kernel<<<dim3(8, 64), 256, 0, stream>>>(qb, kcb, vtc, cntb, ctxb);
  gemm_out<<<dim3(512/128, 16384/128), 256, 0, stream>>>(
      ctxb, woutT, bout, out, pos16, vtc, fsmn_w, NB*NT, ND, ND);
}

// Round 18
// 130.827 us; speedup vs baseline: 1.1707x; 1.1707x over previous
//
#include <hip/hip_runtime.h>
#include <hip/hip_bf16.h>
#include <stdint.h>

// Problem constants (from reference)
#define NB 8
#define NT 2048
#define ND 512
#define NH 4
#define NDK 128
#define QV_LD 1024    // row stride of qvb (Q cols 0..511, V cols 512..1023)
#define KW 11

typedef unsigned short u16;
typedef __attribute__((ext_vector_type(4))) float f32x4;
typedef __attribute__((ext_vector_type(16))) float f32x16;
typedef __attribute__((ext_vector_type(4))) float fv4;
typedef __attribute__((ext_vector_type(8))) short s16x8;   // 8 bf16 = 4 VGPR
typedef __attribute__((ext_vector_type(4))) unsigned short u16x4;
typedef __attribute__((ext_vector_type(4))) int i32x4;

#define AS1 __attribute__((address_space(1)))
#define AS3 __attribute__((address_space(3)))

__device__ __forceinline__ u16 f2bf(float f){
  unsigned u = __float_as_uint(f);
  u += 0x7fffu + ((u >> 16) & 1u);      // RNE
  return (u16)(u >> 16);
}
__device__ __forceinline__ float bf2f(u16 h){ return __uint_as_float(((unsigned)h) << 16); }
__device__ __forceinline__ unsigned pack2bf(float a, float b){
  float2 t; t.x = a; t.y = b;
  __hip_bfloat162 h = __float22bfloat162_rn(t);
  return *reinterpret_cast<unsigned*>(&h);
}

// ---------------------------------------------------------------- fused prep:
// blocks [0,1024): x -> bf16 (grid-stride)
// blocks [1024,1792): Wqkv transpose+cvt; [1792,2048): Wout transpose+cvt
// blocks [2048,2056): per-batch mask scan -> pos16 map (0xFFFF = masked), count
__device__ __forceinline__ void transpose_body(
    const float* __restrict__ in, u16* __restrict__ out, int R, int C,
    int bx, int by, int tid)
{
  __shared__ float tile[32][33];
  const int cb = bx * 32, rb = by * 32;
  const int tx = tid & 31, ty = tid >> 5;   // (32,8)
  #pragma unroll
  for (int i = 0; i < 4; ++i)
    tile[ty + i*8][tx] = in[(size_t)(rb + ty + i*8) * C + cb + tx];
  __syncthreads();
  #pragma unroll
  for (int i = 0; i < 4; ++i)
    out[(size_t)(cb + ty + i*8) * R + rb + tx] = f2bf(tile[tx][ty + i*8]);
}

__global__ void prep_kernel(const float* __restrict__ x, u16* __restrict__ xb,
                            const float* __restrict__ Wqkv, u16* __restrict__ wqkvT,
                            const float* __restrict__ Wout, u16* __restrict__ woutT,
                            const float* __restrict__ mask, u16* __restrict__ pos16,
                            int* __restrict__ cntb)
{
  const int bid = blockIdx.x, tid = threadIdx.x;
  if (bid < 1024){
    const int n4 = (NB*NT*ND)/4;
    for (int i = bid*256 + tid; i < n4; i += 1024*256){
      float4 v = reinterpret_cast<const float4*>(x)[i];
      u16x4 o = { f2bf(v.x), f2bf(v.y), f2bf(v.z), f2bf(v.w) };
      reinterpret_cast<u16x4*>(xb)[i] = o;
    }
  } else if (bid < 1792){
    const int idx = bid - 1024;              // grid (48,16)
    transpose_body(Wqkv, wqkvT, 512, 1536, idx % 48, idx / 48, tid);
  } else if (bid < 2048){
    const int idx = bid - 1792;              // grid (16,16)
    transpose_body(Wout, woutT, 512, 512, idx % 16, idx / 16, tid);
  } else {
    // per-batch mask scan -> pos16 (compact position or 0xFFFF), count
    const int b = bid - 2048;
    __shared__ int s[256];
    const float* mb = mask + (size_t)b * NT;
    float4 a = *reinterpret_cast<const float4*>(&mb[tid*8]);
    float4 c4 = *reinterpret_cast<const float4*>(&mb[tid*8 + 4]);
    float vals[8] = {a.x, a.y, a.z, a.w, c4.x, c4.y, c4.z, c4.w};
    int lc = 0;
    #pragma unroll
    for (int j = 0; j < 8; ++j) lc += (vals[j] != 0.f);
    s[tid] = lc; __syncthreads();
    #pragma unroll
    for (int d = 1; d < 256; d <<= 1){
      const int v = (tid >= d) ? s[tid - d] : 0;
      __syncthreads();
      s[tid] += v;
      __syncthreads();
    }
    const int excl = s[tid] - lc;
    u16* pb = pos16 + (size_t)b * NT;
    int off = excl;
    #pragma unroll
    for (int j = 0; j < 8; ++j){
      const int t = tid*8 + j;
      if (vals[j] != 0.f){ pb[t] = (u16)off; ++off; }
      else pb[t] = (u16)0xFFFF;
    }
    if (tid == 0) cntb[b] = s[255];
  }
}

// ---------------------------------------------------------------- QKV GEMM, fused compaction
// BK=64 + XOR swizzle (rule #21, verified R13). Per-block column range (block-uniform):
//   n0 <  512 : Q -> qvb[row][gc]
//   n0 < 1024 : K -> kcb[bh][pos][dk]  (predicated scatter; pos from pos16)
//   else      : V -> qvb[row][gc-512]  AND  vtc subtiled (predicated scatter)
// Unwritten kcb/vtc tail rows (pos >= cnt) stay garbage: finite, zeroed by attn's
// last-tile predicate -> exact.
__global__ __launch_bounds__(256, 2) void gemm_qkv(
    const u16* __restrict__ A, const u16* __restrict__ Bt, const float* __restrict__ bias,
    const u16* __restrict__ pos16, u16* __restrict__ qvb, u16* __restrict__ kcb,
    u16* __restrict__ vtc)
{
  const int Kd = ND;
  __shared__ u16 As[128 * 64];
  __shared__ u16 Bs[128 * 64];
  const int tid = threadIdx.x;
  const int m0 = blockIdx.y * 128, n0 = blockIdx.x * 128;
  const int w = tid >> 6, l = tid & 63, wr = w >> 1, wc = w & 1;
  const int r15 = l & 15, g = l >> 4;

  f32x4 acc[4][4] = {};

  const int r0 = tid >> 3;
  const int scol8 = ((tid & 7) ^ (r0 & 7)) << 3;
  const u16* Ag = A  + (size_t)(m0 + r0) * Kd + scol8;
  const u16* Bg = Bt + (size_t)(n0 + r0) * Kd + scol8;
  u16* Al = &As[(size_t)tid * 8];
  u16* Bl = &Bs[(size_t)tid * 8];

  for (int k0 = 0; k0 < Kd; k0 += 64){
    #pragma unroll
    for (int i = 0; i < 4; ++i)
      __builtin_amdgcn_global_load_lds((AS1 void*)(Ag + (size_t)(i*32) * Kd + k0),
                                       (AS3 void*)(Al + i*2048), 16, 0, 0);
    #pragma unroll
    for (int i = 0; i < 4; ++i)
      __builtin_amdgcn_global_load_lds((AS1 void*)(Bg + (size_t)(i*32) * Kd + k0),
                                       (AS3 void*)(Bl + i*2048), 16, 0, 0);
    __syncthreads();
    #pragma unroll
    for (int kk = 0; kk < 2; ++kk){
      s16x8 af[4], bfr[4];
      #pragma unroll
      for (int m = 0; m < 4; ++m){
        const int R = wr*64 + m*16 + r15;
        af[m] = *reinterpret_cast<const s16x8*>(&As[R*64 + (((kk*4 + g) ^ (r15 & 7)) << 3)]);
      }
      #pragma unroll
      for (int n = 0; n < 4; ++n){
        const int R = wc*64 + n*16 + r15;
        bfr[n] = *reinterpret_cast<const s16x8*>(&Bs[R*64 + (((kk*4 + g) ^ (r15 & 7)) << 3)]);
      }
      #pragma unroll
      for (int m = 0; m < 4; ++m){
        #pragma unroll
        for (int n = 0; n < 4; ++n)
          acc[m][n] = __builtin_amdgcn_mfma_f32_16x16x32_bf16(af[m], bfr[n], acc[m][n], 0, 0, 0);
      }
    }
    __syncthreads();
  }

  const int range = n0 >> 9;                 // 0=Q, 1=K, 2=V (block-uniform)
  const int bb = m0 >> 11;
  const u16* pb = pos16 + (size_t)bb * NT;
  #pragma unroll
  for (int m = 0; m < 4; ++m){
    const int gr0 = m0 + wr*64 + m*16 + g*4;
    const int tm = gr0 & 2047;
    int pos[4];
    if (range != 0){
      #pragma unroll
      for (int j = 0; j < 4; ++j) pos[j] = (int)pb[tm + j];
    }
    #pragma unroll
    for (int n = 0; n < 4; ++n){
      const int gc = n0 + wc*64 + n*16 + r15;
      const float bv = bias[gc];
      if (range == 0){
        #pragma unroll
        for (int j = 0; j < 4; ++j)
          qvb[(size_t)(gr0 + j) * QV_LD + gc] = f2bf(acc[m][n][j] + bv);
      } else if (range == 1){
        const int d = gc - 512, bh = bb*4 + (d >> 7), dk = d & 127;
        #pragma unroll
        for (int j = 0; j < 4; ++j){
          if (pos[j] != 0xFFFF)
            kcb[((size_t)bh*NT + pos[j])*NDK + dk] = f2bf(acc[m][n][j] + bv);
        }
      } else {
        const int d = gc - 1024, bh = bb*4 + (d >> 7), dk = d & 127;
        #pragma unroll
        for (int j = 0; j < 4; ++j){
          const u16 hv = f2bf(acc[m][n][j] + bv);
          qvb[(size_t)(gr0 + j) * QV_LD + 512 + d] = hv;
          const int p = pos[j];
          if (p != 0xFFFF)
            vtc[((size_t)bh*32 + (p >> 6))*8192 + ((p & 63) >> 3)*1024 + dk*8 + (p & 7)] = hv;
        }
      }
    }
  }
}

// ---------------------------------------------------------------- out GEMM + fused FSMN
// BK=64 + XOR swizzle. FSMN taps read qvb's V half (stride 1024), mask-float zeroing
// (R8/R16-proven pattern). OOB taps zeroed via mk=0; unguarded loads stay in workspace.
__global__ __launch_bounds__(256, 2) void gemm_out(
    const u16* __restrict__ A, const u16* __restrict__ Bt, const float* __restrict__ bias,
    float* __restrict__ Cf, const u16* __restrict__ qvb, const float* __restrict__ mask,
    const float* __restrict__ fsmn_w, int M, int N, int Kd)
{
  __shared__ u16 As[128 * 64];
  __shared__ u16 Bs[128 * 64];
  const int tid = threadIdx.x;
  const int m0 = blockIdx.y * 128, n0 = blockIdx.x * 128;
  const int w = tid >> 6, l = tid & 63, wr = w >> 1, wc = w & 1;
  const int r15 = l & 15, g = l >> 4;

  f32x4 acc[4][4] = {};

  const int r0 = tid >> 3;
  const int scol8 = ((tid & 7) ^ (r0 & 7)) << 3;
  const u16* Ag = A  + (size_t)(m0 + r0) * Kd + scol8;
  const u16* Bg = Bt + (size_t)(n0 + r0) * Kd + scol8;
  u16* Al = &As[(size_t)tid * 8];
  u16* Bl = &Bs[(size_t)tid * 8];

  for (int k0 = 0; k0 < Kd; k0 += 64){
    #pragma unroll
    for (int i = 0; i < 4; ++i)
      __builtin_amdgcn_global_load_lds((AS1 void*)(Ag + (size_t)(i*32) * Kd + k0),
                                       (AS3 void*)(Al + i*2048), 16, 0, 0);
    #pragma unroll
    for (int i = 0; i < 4; ++i)
      __builtin_amdgcn_global_load_lds((AS1 void*)(Bg + (size_t)(i*32) * Kd + k0),
                                       (AS3 void*)(Bl + i*2048), 16, 0, 0);
    __syncthreads();
    #pragma unroll
    for (int kk = 0; kk < 2; ++kk){
      s16x8 af[4], bfr[4];
      #pragma unroll
      for (int m = 0; m < 4; ++m){
        const int R = wr*64 + m*16 + r15;
        af[m] = *reinterpret_cast<const s16x8*>(&As[R*64 + (((kk*4 + g) ^ (r15 & 7)) << 3)]);
      }
      #pragma unroll
      for (int n = 0; n < 4; ++n){
        const int R = wc*64 + n*16 + r15;
        bfr[n] = *reinterpret_cast<const s16x8*>(&Bs[R*64 + (((kk*4 + g) ^ (r15 & 7)) << 3)]);
      }
      #pragma unroll
      for (int m = 0; m < 4; ++m){
        #pragma unroll
        for (int n = 0; n < 4; ++n)
          acc[m][n] = __builtin_amdgcn_mfma_f32_16x16x32_bf16(af[m], bfr[n], acc[m][n], 0, 0, 0);
      }
    }
    __syncthreads();
  }

  float wv[4][KW];
  #pragma unroll
  for (int n = 0; n < 4; ++n){
    const int gc = n0 + wc*64 + n*16 + r15;
    #pragma unroll
    for (int i = 0; i < KW; ++i) wv[n][i] = fsmn_w[gc*KW + i];
  }
  #pragma unroll
  for (int m = 0; m < 4; ++m){
    const int gr0 = m0 + wr*64 + m*16 + g*4;
    const int bb = gr0 >> 11, t0 = gr0 & 2047;
    const float* mb = mask + (size_t)bb * NT;
    float mk[14];
    #pragma unroll
    for (int i = 0; i < 14; ++i){
      const int tau = t0 - 5 + i;
      mk[i] = ((unsigned)tau < (unsigned)NT) ? mb[tau] : 0.f;
    }
    #pragma unroll
    for (int n = 0; n < 4; ++n){
      const int gc = n0 + wc*64 + n*16 + r15;
      const float bv = bias[gc];
      const u16* vb = qvb + (size_t)bb * NT * QV_LD + 512 + gc;
      float vmv[14];
      #pragma unroll
      for (int i = 0; i < 14; ++i){
        const ptrdiff_t tau = t0 - 5 + i;
        vmv[i] = mk[i] * bf2f(vb[tau * QV_LD]);   // mk=0 zeroes OOB taps
      }
      #pragma unroll
      for (int j = 0; j < 4; ++j){
        float conv = vmv[5 + j];                    // vm[t] residual term
        #pragma unroll
        for (int i = 0; i < KW; ++i) conv = fmaf(wv[n][i], vmv[j + i], conv);
        Cf[(size_t)(gr0 + j) * N + gc] = acc[m][n][j] + bv + mk[5 + j] * conv;
      }
    }
  }
}

// ---------------------------------------------------------------- flash attention, COMPACTED KEYS
// R16 structure (verified 63us): ntiles = ceil(cnt/64) runtime; last tile kidx<cnt
// predicate; no mask in inner loop. K rows 256B compact; V subtiled (conflict-free).
// Q from qvb (stride 1024). DO NOT raise launch_bounds 2nd arg (R9 spill lesson).
#define ATT_MFMA(a, bb, c) __builtin_amdgcn_mfma_f32_32x32x16_bf16(a, bb, c, 0, 0, 0)
#define C1F 0.12751741567f   /* (1/sqrt(128)) * log2(e) */

__global__ __launch_bounds__(256, 2) void attn_kernel(
    const u16* __restrict__ qvb, const u16* __restrict__ kcb,
    const u16* __restrict__ vtc, const int* __restrict__ cntb,
    u16* __restrict__ ctxb)
{
  __shared__ u16 Ks[2][64 * 128];   // [key][dk], swizzled 16B chunks
  __shared__ u16 Vs[2][8 * 128 * 8];// [kg][dk][8 keys] subtiled (linear image of vtc tile)
  const int tid = threadIdx.x;
  const int w = tid >> 6, l = tid & 63, l31 = l & 31, hi = l >> 5;

  // XCD-bijective remap: all 16 q-blocks of one bh land on one XCD (K/V L2 locality)
  const int lin = blockIdx.x + blockIdx.y * 8;    // grid = (8, 64)
  const int xcd = lin & 7, jj = lin >> 3;         // jj 0..63
  const int bh = xcd * 4 + (jj & 3), qblk = jj >> 2;
  const int b = bh >> 2, h = bh & 3;
  const int q0 = qblk * 128;

  const u16* kb   = kcb + (size_t)bh * NT * NDK;
  const u16* vtb  = vtc + (size_t)bh * 32 * 8192;
  const int total = cntb[b];
  const int ntiles = (total + 63) >> 6;

  // Q in registers (B-operand): lane holds Q[q0+w*32+l31][s*16 + hi*8 .. +7]
  s16x8 qf[8];
  {
    const u16* qrow = qvb + (size_t)(b*NT + q0 + w*32 + l31) * QV_LD + h * NDK;
    #pragma unroll
    for (int s = 0; s < 8; ++s)
      qf[s] = *reinterpret_cast<const s16x8*>(qrow + s*16 + hi*8);
  }

  float mrun = -1e30f, lrun = 0.f;
  f32x16 o0 = {}, o1 = {}, o2 = {}, o3 = {};

#define STAGE(buf, kvo) do { \
    _Pragma("unroll") \
    for (int i_ = 0; i_ < 4; ++i_){ \
      const int n_ = i_*256 + tid, kr_ = n_ >> 4, c_ = n_ & 15; \
      const u16* gp_ = kb + (size_t)((kvo) + kr_) * NDK + ((c_ ^ (kr_ & 7)) << 3); \
      __builtin_amdgcn_global_load_lds((AS1 void*)gp_, (AS3 void*)&Ks[buf][n_*8], 16, 0, 0); \
    } \
    const u16* vsrc_ = vtb + ((kvo) >> 6) * 8192; \
    _Pragma("unroll") \
    for (int i_ = 0; i_ < 4; ++i_){ \
      const int n_ = i_*256 + tid; \
      __builtin_amdgcn_global_load_lds((AS1 void*)(vsrc_ + n_*8), \
                                       (AS3 void*)&Vs[buf][n_*8], 16, 0, 0); \
    } \
  } while(0)

  if (ntiles > 0) STAGE(0, 0);
  __syncthreads();
  int cur = 0;

  for (int t = 0; t < ntiles; ++t){
    const int kv0 = t * 64;
    if (t + 1 < ntiles) STAGE(cur ^ 1, kv0 + 64);

    // S^T = K Q^T: d0 keys kv0+0..31, d1 keys kv0+32..63; lane owns q-col l31
    f32x16 d0 = {}, d1 = {};
    __builtin_amdgcn_s_setprio(1);
    #pragma unroll
    for (int s = 0; s < 8; ++s){
      const int cg = s*2 + hi;
      s16x8 kf0 = *reinterpret_cast<const s16x8*>(
          &Ks[cur][ l31*128      + ((cg ^ (l31 & 7)) << 3) ]);
      s16x8 kf1 = *reinterpret_cast<const s16x8*>(
          &Ks[cur][ (32+l31)*128 + ((cg ^ (l31 & 7)) << 3) ]);
      d0 = ATT_MFMA(kf0, qf[s], d0);
      d1 = ATT_MFMA(kf1, qf[s], d1);
    }
    __builtin_amdgcn_s_setprio(0);

    // row max over raw scores: max3-friendly tree, then cross-half
    float mx0 = fmaxf(d0[0], d0[1]), mx1 = fmaxf(d0[2], d0[3]);
    float mx2 = fmaxf(d1[0], d1[1]), mx3 = fmaxf(d1[2], d1[3]);
    #pragma unroll
    for (int r = 4; r < 16; r += 4){
      mx0 = fmaxf(mx0, fmaxf(d0[r],   d0[r+1]));
      mx1 = fmaxf(mx1, fmaxf(d0[r+2], d0[r+3]));
      mx2 = fmaxf(mx2, fmaxf(d1[r],   d1[r+1]));
      mx3 = fmaxf(mx3, fmaxf(d1[r+2], d1[r+3]));
    }
    float tmx = fmaxf(fmaxf(mx0, mx1), fmaxf(mx2, mx3));
    tmx = fmaxf(tmx, __shfl_xor(tmx, 32));

    // T13 defer-max (raw-score threshold 64 ~ 8 nats)
    if (!__all(tmx <= mrun + 64.f)){
      const float mn = fmaxf(mrun, tmx);
      const float corr = __builtin_amdgcn_exp2f((mrun - mn) * C1F);
      mrun = mn; lrun *= corr;
      #pragma unroll
      for (int r = 0; r < 16; ++r){
        const int qs = (r & 3) + 8*(r >> 2) + 4*hi;
        const float cq = __shfl(corr, qs);
        o0[r] *= cq; o1[r] *= cq; o2[r] *= cq; o3[r] *= cq;
      }
    }

    // p = exp2(fma(s, c1, -m*c1)); no mask (keys pre-compacted); last tile: kidx<cnt
    const float mm = mrun * C1F;
    float ts = 0.f;
    if (t + 1 < ntiles){
      #pragma unroll
      for (int r = 0; r < 16; ++r){
        const float p0 = __builtin_amdgcn_exp2f(fmaf(d0[r], C1F, -mm));
        const float p1 = __builtin_amdgcn_exp2f(fmaf(d1[r], C1F, -mm));
        d0[r] = p0; d1[r] = p1; ts += p0 + p1;
      }
    } else {
      #pragma unroll
      for (int r = 0; r < 16; ++r){
        const int kidx = kv0 + (r >> 2)*8 + 4*hi + (r & 3);
        const float p0 = (kidx      < total) ? __builtin_amdgcn_exp2f(fmaf(d0[r], C1F, -mm)) : 0.f;
        const float p1 = (kidx + 32 < total) ? __builtin_amdgcn_exp2f(fmaf(d1[r], C1F, -mm)) : 0.f;
        d0[r] = p0; d1[r] = p1; ts += p0 + p1;
      }
    }
    ts += __shfl_xor(ts, 32);
    lrun += ts;

    // pack p -> bf16 pairs
    unsigned pku[2][4][2];
    #pragma unroll
    for (int r8 = 0; r8 < 4; ++r8){
      pku[0][r8][0] = pack2bf(d0[4*r8+0], d0[4*r8+1]);
      pku[0][r8][1] = pack2bf(d0[4*r8+2], d0[4*r8+3]);
      pku[1][r8][0] = pack2bf(d1[4*r8+0], d1[4*r8+1]);
      pku[1][r8][1] = pack2bf(d1[4*r8+2], d1[4*r8+3]);
    }

    // PV: per k-step build A-frag with 2 permlane32_swap, then 4 dk-blocks.
    const int vb0 = hi*1024 + l31*8;
    #pragma unroll
    for (int ks = 0; ks < 4; ++ks){
      const int bb = ks >> 1, rlo = (ks & 1) * 2;
      int u0 = (int)pku[bb][rlo][0],   u1 = (int)pku[bb][rlo][1];
      int v0 = (int)pku[bb][rlo+1][0], v1 = (int)pku[bb][rlo+1][1];
      asm("v_permlane32_swap_b32 %0, %1" : "+v"(u0), "+v"(v0));
      asm("v_permlane32_swap_b32 %0, %1" : "+v"(u1), "+v"(v1));
      union { i32x4 i; s16x8 hv; } pu;
      pu.i[0] = u0; pu.i[1] = u1; pu.i[2] = v0; pu.i[3] = v1;
      const int off = ks*2048 + vb0;
      s16x8 vf0 = *reinterpret_cast<const s16x8*>(&Vs[cur][ off       ]);
      s16x8 vf1 = *reinterpret_cast<const s16x8*>(&Vs[cur][ off + 256 ]);
      s16x8 vf2 = *reinterpret_cast<const s16x8*>(&Vs[cur][ off + 512 ]);
      s16x8 vf3 = *reinterpret_cast<const s16x8*>(&Vs[cur][ off + 768 ]);
      __builtin_amdgcn_s_setprio(1);
      o0 = ATT_MFMA(pu.hv, vf0, o0);
      o1 = ATT_MFMA(pu.hv, vf1, o1);
      o2 = ATT_MFMA(pu.hv, vf2, o2);
      o3 = ATT_MFMA(pu.hv, vf3, o3);
      __builtin_amdgcn_s_setprio(0);
    }

    __syncthreads();
    cur ^= 1;
  }

  // epilogue: O[q][dk] regs: col dk = dkblk*32 + l31, row q = (r&3)+8*(r>>2)+4*hi
  #pragma unroll
  for (int r = 0; r < 16; ++r){
    const int qs = (r & 3) + 8*(r >> 2) + 4*hi;
    const float lr = __shfl(lrun, qs);
    const float rl = (lr > 0.f) ? (1.f / lr) : 0.f;
    const int row = q0 + w*32 + qs;
    u16* cp = ctxb + (size_t)(b*NT + row) * ND + h*NDK + l31;
    cp[0]  = f2bf(o0[r] * rl);
    cp[32] = f2bf(o1[r] * rl);
    cp[64] = f2bf(o2[r] * rl);
    cp[96] = f2bf(o3[r] * rl);
  }
#undef STAGE
}

// ---------------------------------------------------------------- launcher
extern "C" void kernel_launch(void* const* d_in, const int* in_sizes, int n_in,
                              void* d_out, int out_size, void* d_ws, size_t ws_size,
                              hipStream_t stream) {
  const float* x      = (const float*)d_in[0];
  const float* mask   = (const float*)d_in[1];
  const float* Wqkv   = (const float*)d_in[2];
  const float* bqkv   = (const float*)d_in[3];
  const float* Wout   = (const float*)d_in[4];
  const float* bout   = (const float*)d_in[5];
  const float* fsmn_w = (const float*)d_in[6];
  float* out = (float*)d_out;

  // workspace layout (bytes), total ~103 MB
  char* ws = (char*)d_ws;
  u16* xb    = (u16*)ws;                         // 16,777,216
  u16* wqkvT = (u16*)(ws + 16777216);            //  1,572,864
  u16* woutT = (u16*)(ws + 18350080);            //    524,288
  u16* qvb   = (u16*)(ws + 18874368);            // 33,554,432  (16384 x 1024 bf16)
  u16* kcb   = (u16*)(ws + 52428800);            // 16,777,216
  u16* vtc   = (u16*)(ws + 69206016);            // 16,777,216
  u16* ctxb  = (u16*)(ws + 85983232);            // 16,777,216
  u16* pos16 = (u16*)(ws + 102760448);           //     32,768
  int* cntb  = (int*)(ws + 102793216);           //         32

  prep_kernel<<<2056, 256, 0, stream>>>(x, xb, Wqkv, wqkvT, Wout, woutT,
                                        mask, pos16, cntb);
  gemm_qkv<<<dim3(1536/128, 16384/128), 256, 0, stream>>>(
      xb, wqkvT, bqkv, pos16, qvb, kcb, vtc);
  attn_kernel<<<dim3(8, 64), 256, 0, stream>>>(qvb, kcb, vtc, cntb, ctxb);
  gemm_out<<<dim3(512/128, 16384/128), 256, 0, stream>>>(
      ctxb, woutT, bout, out, qvb, mask, fsmn_w, NB*NT, ND, ND);
}

// Round 19
// 125.688 us; speedup vs baseline: 1.2185x; 1.0409x over previous
//
#include <hip/hip_runtime.h>
#include <hip/hip_bf16.h>
#include <stdint.h>

// Problem constants (from reference)
#define NB 8
#define NT 2048
#define ND 512
#define NH 4
#define NDK 128
#define QV_LD 1024    // row stride of qvb (Q cols 0..511, V cols 512..1023)
#define KW 11
#define C1F 0.12751741567f   /* (1/sqrt(128)) * log2(e), folded into stored Q */

typedef unsigned short u16;
typedef __attribute__((ext_vector_type(4))) float f32x4;
typedef __attribute__((ext_vector_type(16))) float f32x16;
typedef __attribute__((ext_vector_type(4))) float fv4;
typedef __attribute__((ext_vector_type(8))) short s16x8;   // 8 bf16 = 4 VGPR
typedef __attribute__((ext_vector_type(4))) unsigned short u16x4;
typedef __attribute__((ext_vector_type(4))) int i32x4;

#define AS1 __attribute__((address_space(1)))
#define AS3 __attribute__((address_space(3)))

__device__ __forceinline__ u16 f2bf(float f){
  unsigned u = __float_as_uint(f);
  u += 0x7fffu + ((u >> 16) & 1u);      // RNE
  return (u16)(u >> 16);
}
__device__ __forceinline__ float bf2f(u16 h){ return __uint_as_float(((unsigned)h) << 16); }
__device__ __forceinline__ unsigned pack2bf(float a, float b){
  float2 t; t.x = a; t.y = b;
  __hip_bfloat162 h = __float22bfloat162_rn(t);
  return *reinterpret_cast<unsigned*>(&h);
}

// ---------------------------------------------------------------- fused prep:
// blocks [0,1024): x -> bf16 (grid-stride)
// blocks [1024,1792): Wqkv transpose+cvt; [1792,2048): Wout transpose+cvt
// blocks [2048,2056): per-batch mask scan -> pos16 map (0xFFFF = masked), count
__device__ __forceinline__ void transpose_body(
    const float* __restrict__ in, u16* __restrict__ out, int R, int C,
    int bx, int by, int tid)
{
  __shared__ float tile[32][33];
  const int cb = bx * 32, rb = by * 32;
  const int tx = tid & 31, ty = tid >> 5;   // (32,8)
  #pragma unroll
  for (int i = 0; i < 4; ++i)
    tile[ty + i*8][tx] = in[(size_t)(rb + ty + i*8) * C + cb + tx];
  __syncthreads();
  #pragma unroll
  for (int i = 0; i < 4; ++i)
    out[(size_t)(cb + ty + i*8) * R + rb + tx] = f2bf(tile[tx][ty + i*8]);
}

__global__ void prep_kernel(const float* __restrict__ x, u16* __restrict__ xb,
                            const float* __restrict__ Wqkv, u16* __restrict__ wqkvT,
                            const float* __restrict__ Wout, u16* __restrict__ woutT,
                            const float* __restrict__ mask, u16* __restrict__ pos16,
                            int* __restrict__ cntb)
{
  const int bid = blockIdx.x, tid = threadIdx.x;
  if (bid < 1024){
    const int n4 = (NB*NT*ND)/4;
    for (int i = bid*256 + tid; i < n4; i += 1024*256){
      float4 v = reinterpret_cast<const float4*>(x)[i];
      u16x4 o = { f2bf(v.x), f2bf(v.y), f2bf(v.z), f2bf(v.w) };
      reinterpret_cast<u16x4*>(xb)[i] = o;
    }
  } else if (bid < 1792){
    const int idx = bid - 1024;              // grid (48,16)
    transpose_body(Wqkv, wqkvT, 512, 1536, idx % 48, idx / 48, tid);
  } else if (bid < 2048){
    const int idx = bid - 1792;              // grid (16,16)
    transpose_body(Wout, woutT, 512, 512, idx % 16, idx / 16, tid);
  } else {
    // per-batch mask scan -> pos16 (compact position or 0xFFFF), count
    const int b = bid - 2048;
    __shared__ int s[256];
    const float* mb = mask + (size_t)b * NT;
    float4 a = *reinterpret_cast<const float4*>(&mb[tid*8]);
    float4 c4 = *reinterpret_cast<const float4*>(&mb[tid*8 + 4]);
    float vals[8] = {a.x, a.y, a.z, a.w, c4.x, c4.y, c4.z, c4.w};
    int lc = 0;
    #pragma unroll
    for (int j = 0; j < 8; ++j) lc += (vals[j] != 0.f);
    s[tid] = lc; __syncthreads();
    #pragma unroll
    for (int d = 1; d < 256; d <<= 1){
      const int v = (tid >= d) ? s[tid - d] : 0;
      __syncthreads();
      s[tid] += v;
      __syncthreads();
    }
    const int excl = s[tid] - lc;
    u16* pb = pos16 + (size_t)b * NT;
    int off = excl;
    #pragma unroll
    for (int j = 0; j < 8; ++j){
      const int t = tid*8 + j;
      if (vals[j] != 0.f){ pb[t] = (u16)off; ++off; }
      else pb[t] = (u16)0xFFFF;
    }
    if (tid == 0) cntb[b] = s[255];
  }
}

// ---------------------------------------------------------------- QKV GEMM, fused compaction
// BK=64 + XOR swizzle (rule #21, verified R13). Per-block column range (block-uniform):
//   n0 <  512 : Q -> qvb[row][gc], PRE-SCALED by C1F (softmax exp2 arg folded in)
//   n0 < 1024 : K -> kcb[bh][pos][dk]  (predicated scatter; pos from pos16)
//   else      : V -> qvb[row][gc-512]  AND  vtc subtiled (predicated scatter)
// Unwritten kcb/vtc tail rows (pos >= cnt) stay garbage: finite, zeroed by attn's
// last-tile predicate -> exact.
__global__ __launch_bounds__(256, 2) void gemm_qkv(
    const u16* __restrict__ A, const u16* __restrict__ Bt, const float* __restrict__ bias,
    const u16* __restrict__ pos16, u16* __restrict__ qvb, u16* __restrict__ kcb,
    u16* __restrict__ vtc)
{
  const int Kd = ND;
  __shared__ u16 As[128 * 64];
  __shared__ u16 Bs[128 * 64];
  const int tid = threadIdx.x;
  const int m0 = blockIdx.y * 128, n0 = blockIdx.x * 128;
  const int w = tid >> 6, l = tid & 63, wr = w >> 1, wc = w & 1;
  const int r15 = l & 15, g = l >> 4;

  f32x4 acc[4][4] = {};

  const int r0 = tid >> 3;
  const int scol8 = ((tid & 7) ^ (r0 & 7)) << 3;
  const u16* Ag = A  + (size_t)(m0 + r0) * Kd + scol8;
  const u16* Bg = Bt + (size_t)(n0 + r0) * Kd + scol8;
  u16* Al = &As[(size_t)tid * 8];
  u16* Bl = &Bs[(size_t)tid * 8];

  for (int k0 = 0; k0 < Kd; k0 += 64){
    #pragma unroll
    for (int i = 0; i < 4; ++i)
      __builtin_amdgcn_global_load_lds((AS1 void*)(Ag + (size_t)(i*32) * Kd + k0),
                                       (AS3 void*)(Al + i*2048), 16, 0, 0);
    #pragma unroll
    for (int i = 0; i < 4; ++i)
      __builtin_amdgcn_global_load_lds((AS1 void*)(Bg + (size_t)(i*32) * Kd + k0),
                                       (AS3 void*)(Bl + i*2048), 16, 0, 0);
    __syncthreads();
    #pragma unroll
    for (int kk = 0; kk < 2; ++kk){
      s16x8 af[4], bfr[4];
      #pragma unroll
      for (int m = 0; m < 4; ++m){
        const int R = wr*64 + m*16 + r15;
        af[m] = *reinterpret_cast<const s16x8*>(&As[R*64 + (((kk*4 + g) ^ (r15 & 7)) << 3)]);
      }
      #pragma unroll
      for (int n = 0; n < 4; ++n){
        const int R = wc*64 + n*16 + r15;
        bfr[n] = *reinterpret_cast<const s16x8*>(&Bs[R*64 + (((kk*4 + g) ^ (r15 & 7)) << 3)]);
      }
      #pragma unroll
      for (int m = 0; m < 4; ++m){
        #pragma unroll
        for (int n = 0; n < 4; ++n)
          acc[m][n] = __builtin_amdgcn_mfma_f32_16x16x32_bf16(af[m], bfr[n], acc[m][n], 0, 0, 0);
      }
    }
    __syncthreads();
  }

  const int range = n0 >> 9;                 // 0=Q, 1=K, 2=V (block-uniform)
  const int bb = m0 >> 11;
  const u16* pb = pos16 + (size_t)bb * NT;
  #pragma unroll
  for (int m = 0; m < 4; ++m){
    const int gr0 = m0 + wr*64 + m*16 + g*4;
    const int tm = gr0 & 2047;
    int pos[4];
    if (range != 0){
      #pragma unroll
      for (int j = 0; j < 4; ++j) pos[j] = (int)pb[tm + j];
    }
    #pragma unroll
    for (int n = 0; n < 4; ++n){
      const int gc = n0 + wc*64 + n*16 + r15;
      const float bv = bias[gc];
      if (range == 0){
        #pragma unroll
        for (int j = 0; j < 4; ++j)
          qvb[(size_t)(gr0 + j) * QV_LD + gc] = f2bf((acc[m][n][j] + bv) * C1F);
      } else if (range == 1){
        const int d = gc - 512, bh = bb*4 + (d >> 7), dk = d & 127;
        #pragma unroll
        for (int j = 0; j < 4; ++j){
          if (pos[j] != 0xFFFF)
            kcb[((size_t)bh*NT + pos[j])*NDK + dk] = f2bf(acc[m][n][j] + bv);
        }
      } else {
        const int d = gc - 1024, bh = bb*4 + (d >> 7), dk = d & 127;
        #pragma unroll
        for (int j = 0; j < 4; ++j){
          const u16 hv = f2bf(acc[m][n][j] + bv);
          qvb[(size_t)(gr0 + j) * QV_LD + 512 + d] = hv;
          const int p = pos[j];
          if (p != 0xFFFF)
            vtc[((size_t)bh*32 + (p >> 6))*8192 + ((p & 63) >> 3)*1024 + dk*8 + (p & 7)] = hv;
        }
      }
    }
  }
}

// ---------------------------------------------------------------- out GEMM + fused FSMN
// BK=64 + XOR swizzle. FSMN taps read qvb's V half (stride 1024), mask-float zeroing
// (R8/R16-proven pattern). OOB taps zeroed via mk=0; unguarded loads stay in workspace.
__global__ __launch_bounds__(256, 2) void gemm_out(
    const u16* __restrict__ A, const u16* __restrict__ Bt, const float* __restrict__ bias,
    float* __restrict__ Cf, const u16* __restrict__ qvb, const float* __restrict__ mask,
    const float* __restrict__ fsmn_w, int M, int N, int Kd)
{
  __shared__ u16 As[128 * 64];
  __shared__ u16 Bs[128 * 64];
  const int tid = threadIdx.x;
  const int m0 = blockIdx.y * 128, n0 = blockIdx.x * 128;
  const int w = tid >> 6, l = tid & 63, wr = w >> 1, wc = w & 1;
  const int r15 = l & 15, g = l >> 4;

  f32x4 acc[4][4] = {};

  const int r0 = tid >> 3;
  const int scol8 = ((tid & 7) ^ (r0 & 7)) << 3;
  const u16* Ag = A  + (size_t)(m0 + r0) * Kd + scol8;
  const u16* Bg = Bt + (size_t)(n0 + r0) * Kd + scol8;
  u16* Al = &As[(size_t)tid * 8];
  u16* Bl = &Bs[(size_t)tid * 8];

  for (int k0 = 0; k0 < Kd; k0 += 64){
    #pragma unroll
    for (int i = 0; i < 4; ++i)
      __builtin_amdgcn_global_load_lds((AS1 void*)(Ag + (size_t)(i*32) * Kd + k0),
                                       (AS3 void*)(Al + i*2048), 16, 0, 0);
    #pragma unroll
    for (int i = 0; i < 4; ++i)
      __builtin_amdgcn_global_load_lds((AS1 void*)(Bg + (size_t)(i*32) * Kd + k0),
                                       (AS3 void*)(Bl + i*2048), 16, 0, 0);
    __syncthreads();
    #pragma unroll
    for (int kk = 0; kk < 2; ++kk){
      s16x8 af[4], bfr[4];
      #pragma unroll
      for (int m = 0; m < 4; ++m){
        const int R = wr*64 + m*16 + r15;
        af[m] = *reinterpret_cast<const s16x8*>(&As[R*64 + (((kk*4 + g) ^ (r15 & 7)) << 3)]);
      }
      #pragma unroll
      for (int n = 0; n < 4; ++n){
        const int R = wc*64 + n*16 + r15;
        bfr[n] = *reinterpret_cast<const s16x8*>(&Bs[R*64 + (((kk*4 + g) ^ (r15 & 7)) << 3)]);
      }
      #pragma unroll
      for (int m = 0; m < 4; ++m){
        #pragma unroll
        for (int n = 0; n < 4; ++n)
          acc[m][n] = __builtin_amdgcn_mfma_f32_16x16x32_bf16(af[m], bfr[n], acc[m][n], 0, 0, 0);
      }
    }
    __syncthreads();
  }

  float wv[4][KW];
  #pragma unroll
  for (int n = 0; n < 4; ++n){
    const int gc = n0 + wc*64 + n*16 + r15;
    #pragma unroll
    for (int i = 0; i < KW; ++i) wv[n][i] = fsmn_w[gc*KW + i];
  }
  #pragma unroll
  for (int m = 0; m < 4; ++m){
    const int gr0 = m0 + wr*64 + m*16 + g*4;
    const int bb = gr0 >> 11, t0 = gr0 & 2047;
    const float* mb = mask + (size_t)bb * NT;
    float mk[14];
    #pragma unroll
    for (int i = 0; i < 14; ++i){
      const int tau = t0 - 5 + i;
      mk[i] = ((unsigned)tau < (unsigned)NT) ? mb[tau] : 0.f;
    }
    #pragma unroll
    for (int n = 0; n < 4; ++n){
      const int gc = n0 + wc*64 + n*16 + r15;
      const float bv = bias[gc];
      const u16* vb = qvb + (size_t)bb * NT * QV_LD + 512 + gc;
      float vmv[14];
      #pragma unroll
      for (int i = 0; i < 14; ++i){
        const ptrdiff_t tau = t0 - 5 + i;
        vmv[i] = mk[i] * bf2f(vb[tau * QV_LD]);   // mk=0 zeroes OOB taps
      }
      #pragma unroll
      for (int j = 0; j < 4; ++j){
        float conv = vmv[5 + j];                    // vm[t] residual term
        #pragma unroll
        for (int i = 0; i < KW; ++i) conv = fmaf(wv[n][i], vmv[j + i], conv);
        Cf[(size_t)(gr0 + j) * N + gc] = acc[m][n][j] + bv + mk[5 + j] * conv;
      }
    }
  }
}

// ---------------------------------------------------------------- flash attention, COMPACTED KEYS
// R16/R18 structure + NO-MAX softmax: raw scores have sigma~2.3, |d·C1F| << f32 exp2
// range, and softmax is shift-invariant -> subtract nothing. Q is pre-scaled by C1F in
// gemm_qkv, so p = v_exp(d) directly. No max tree, no cross-half sync before exp, no
// defer-max/rescale; lrun is lane-local (one shfl_xor in the epilogue).
// Last tile: kidx<cnt predicate zeroes garbage keys (also guards their exp inputs).
// DO NOT raise launch_bounds 2nd arg (R9 spill lesson).
#define ATT_MFMA(a, bb, c) __builtin_amdgcn_mfma_f32_32x32x16_bf16(a, bb, c, 0, 0, 0)

__global__ __launch_bounds__(256, 2) void attn_kernel(
    const u16* __restrict__ qvb, const u16* __restrict__ kcb,
    const u16* __restrict__ vtc, const int* __restrict__ cntb,
    u16* __restrict__ ctxb)
{
  __shared__ u16 Ks[2][64 * 128];   // [key][dk], swizzled 16B chunks
  __shared__ u16 Vs[2][8 * 128 * 8];// [kg][dk][8 keys] subtiled (linear image of vtc tile)
  const int tid = threadIdx.x;
  const int w = tid >> 6, l = tid & 63, l31 = l & 31, hi = l >> 5;

  // XCD-bijective remap: all 16 q-blocks of one bh land on one XCD (K/V L2 locality)
  const int lin = blockIdx.x + blockIdx.y * 8;    // grid = (8, 64)
  const int xcd = lin & 7, jj = lin >> 3;         // jj 0..63
  const int bh = xcd * 4 + (jj & 3), qblk = jj >> 2;
  const int b = bh >> 2, h = bh & 3;
  const int q0 = qblk * 128;

  const u16* kb   = kcb + (size_t)bh * NT * NDK;
  const u16* vtb  = vtc + (size_t)bh * 32 * 8192;
  const int total = cntb[b];
  const int ntiles = (total + 63) >> 6;

  // Q in registers (B-operand): lane holds Q[q0+w*32+l31][s*16 + hi*8 .. +7]
  s16x8 qf[8];
  {
    const u16* qrow = qvb + (size_t)(b*NT + q0 + w*32 + l31) * QV_LD + h * NDK;
    #pragma unroll
    for (int s = 0; s < 8; ++s)
      qf[s] = *reinterpret_cast<const s16x8*>(qrow + s*16 + hi*8);
  }

  float lrun = 0.f;                 // lane-local; cross-half summed in epilogue
  f32x16 o0 = {}, o1 = {}, o2 = {}, o3 = {};

#define STAGE(buf, kvo) do { \
    _Pragma("unroll") \
    for (int i_ = 0; i_ < 4; ++i_){ \
      const int n_ = i_*256 + tid, kr_ = n_ >> 4, c_ = n_ & 15; \
      const u16* gp_ = kb + (size_t)((kvo) + kr_) * NDK + ((c_ ^ (kr_ & 7)) << 3); \
      __builtin_amdgcn_global_load_lds((AS1 void*)gp_, (AS3 void*)&Ks[buf][n_*8], 16, 0, 0); \
    } \
    const u16* vsrc_ = vtb + ((kvo) >> 6) * 8192; \
    _Pragma("unroll") \
    for (int i_ = 0; i_ < 4; ++i_){ \
      const int n_ = i_*256 + tid; \
      __builtin_amdgcn_global_load_lds((AS1 void*)(vsrc_ + n_*8), \
                                       (AS3 void*)&Vs[buf][n_*8], 16, 0, 0); \
    } \
  } while(0)

  if (ntiles > 0) STAGE(0, 0);
  __syncthreads();
  int cur = 0;

  for (int t = 0; t < ntiles; ++t){
    const int kv0 = t * 64;
    if (t + 1 < ntiles) STAGE(cur ^ 1, kv0 + 64);

    // S^T = K Q^T: d0 keys kv0+0..31, d1 keys kv0+32..63; lane owns q-col l31
    f32x16 d0 = {}, d1 = {};
    __builtin_amdgcn_s_setprio(1);
    #pragma unroll
    for (int s = 0; s < 8; ++s){
      const int cg = s*2 + hi;
      s16x8 kf0 = *reinterpret_cast<const s16x8*>(
          &Ks[cur][ l31*128      + ((cg ^ (l31 & 7)) << 3) ]);
      s16x8 kf1 = *reinterpret_cast<const s16x8*>(
          &Ks[cur][ (32+l31)*128 + ((cg ^ (l31 & 7)) << 3) ]);
      d0 = ATT_MFMA(kf0, qf[s], d0);
      d1 = ATT_MFMA(kf1, qf[s], d1);
    }
    __builtin_amdgcn_s_setprio(0);

    // p = exp2(d) directly (Q pre-scaled; no max subtraction -- shift-invariant and
    // |d| is tiny vs f32 exp2 range). Last tile: kidx<cnt predicate.
    float ts = 0.f;
    if (t + 1 < ntiles){
      #pragma unroll
      for (int r = 0; r < 16; ++r){
        const float p0 = __builtin_amdgcn_exp2f(d0[r]);
        const float p1 = __builtin_amdgcn_exp2f(d1[r]);
        d0[r] = p0; d1[r] = p1; ts += p0 + p1;
      }
    } else {
      #pragma unroll
      for (int r = 0; r < 16; ++r){
        const int kidx = kv0 + (r >> 2)*8 + 4*hi + (r & 3);
        const float p0 = (kidx      < total) ? __builtin_amdgcn_exp2f(d0[r]) : 0.f;
        const float p1 = (kidx + 32 < total) ? __builtin_amdgcn_exp2f(d1[r]) : 0.f;
        d0[r] = p0; d1[r] = p1; ts += p0 + p1;
      }
    }
    lrun += ts;

    // pack p -> bf16 pairs
    unsigned pku[2][4][2];
    #pragma unroll
    for (int r8 = 0; r8 < 4; ++r8){
      pku[0][r8][0] = pack2bf(d0[4*r8+0], d0[4*r8+1]);
      pku[0][r8][1] = pack2bf(d0[4*r8+2], d0[4*r8+3]);
      pku[1][r8][0] = pack2bf(d1[4*r8+0], d1[4*r8+1]);
      pku[1][r8][1] = pack2bf(d1[4*r8+2], d1[4*r8+3]);
    }

    // PV: per k-step build A-frag with 2 permlane32_swap, then 4 dk-blocks.
    const int vb0 = hi*1024 + l31*8;
    #pragma unroll
    for (int ks = 0; ks < 4; ++ks){
      const int bb = ks >> 1, rlo = (ks & 1) * 2;
      int u0 = (int)pku[bb][rlo][0],   u1 = (int)pku[bb][rlo][1];
      int v0 = (int)pku[bb][rlo+1][0], v1 = (int)pku[bb][rlo+1][1];
      asm("v_permlane32_swap_b32 %0, %1" : "+v"(u0), "+v"(v0));
      asm("v_permlane32_swap_b32 %0, %1" : "+v"(u1), "+v"(v1));
      union { i32x4 i; s16x8 hv; } pu;
      pu.i[0] = u0; pu.i[1] = u1; pu.i[2] = v0; pu.i[3] = v1;
      const int off = ks*2048 + vb0;
      s16x8 vf0 = *reinterpret_cast<const s16x8*>(&Vs[cur][ off       ]);
      s16x8 vf1 = *reinterpret_cast<const s16x8*>(&Vs[cur][ off + 256 ]);
      s16x8 vf2 = *reinterpret_cast<const s16x8*>(&Vs[cur][ off + 512 ]);
      s16x8 vf3 = *reinterpret_cast<const s16x8*>(&Vs[cur][ off + 768 ]);
      __builtin_amdgcn_s_setprio(1);
      o0 = ATT_MFMA(pu.hv, vf0, o0);
      o1 = ATT_MFMA(pu.hv, vf1, o1);
      o2 = ATT_MFMA(pu.hv, vf2, o2);
      o3 = ATT_MFMA(pu.hv, vf3, o3);
      __builtin_amdgcn_s_setprio(0);
    }

    __syncthreads();
    cur ^= 1;
  }

  // epilogue: cross-half l sum once; O rows q = (r&3)+8*(r>>2)+4*hi, col dk = blk*32+l31
  const float lsum = lrun + __shfl_xor(lrun, 32);
  #pragma unroll
  for (int r = 0; r < 16; ++r){
    const int qs = (r & 3) + 8*(r >> 2) + 4*hi;
    const float lr = __shfl(lsum, qs);
    const float rl = (lr > 0.f) ? (1.f / lr) : 0.f;
    const int row = q0 + w*32 + qs;
    u16* cp = ctxb + (size_t)(b*NT + row) * ND + h*NDK + l31;
    cp[0]  = f2bf(o0[r] * rl);
    cp[32] = f2bf(o1[r] * rl);
    cp[64] = f2bf(o2[r] * rl);
    cp[96] = f2bf(o3[r] * rl);
  }
#undef STAGE
}

// ---------------------------------------------------------------- launcher
extern "C" void kernel_launch(void* const* d_in, const int* in_sizes, int n_in,
                              void* d_out, int out_size, void* d_ws, size_t ws_size,
                              hipStream_t stream) {
  const float* x      = (const float*)d_in[0];
  const float* mask   = (const float*)d_in[1];
  const float* Wqkv   = (const float*)d_in[2];
  const float* bqkv   = (const float*)d_in[3];
  const float* Wout   = (const float*)d_in[4];
  const float* bout   = (const float*)d_in[5];
  const float* fsmn_w = (const float*)d_in[6];
  float* out = (float*)d_out;

  // workspace layout (bytes), total ~103 MB
  char* ws = (char*)d_ws;
  u16* xb    = (u16*)ws;                         // 16,777,216
  u16* wqkvT = (u16*)(ws + 16777216);            //  1,572,864
  u16* woutT = (u16*)(ws + 18350080);            //    524,288
  u16* qvb   = (u16*)(ws + 18874368);            // 33,554,432  (16384 x 1024 bf16)
  u16* kcb   = (u16*)(ws + 52428800);            // 16,777,216
  u16* vtc   = (u16*)(ws + 69206016);            // 16,777,216
  u16* ctxb  = (u16*)(ws + 85983232);            // 16,777,216
  u16* pos16 = (u16*)(ws + 102760448);           //     32,768
  int* cntb  = (int*)(ws + 102793216);           //         32

  prep_kernel<<<2056, 256, 0, stream>>>(x, xb, Wqkv, wqkvT, Wout, woutT,
                                        mask, pos16, cntb);
  gemm_qkv<<<dim3(1536/128, 16384/128), 256, 0, stream>>>(
      xb, wqkvT, bqkv, pos16, qvb, kcb, vtc);
  attn_kernel<<<dim3(8, 64), 256, 0, stream>>>(qvb, kcb, vtc, cntb, ctxb);
  gemm_out<<<dim3(512/128, 16384/128), 256, 0, stream>>>(
      ctxb, woutT, bout, out, qvb, mask, fsmn_w, NB*NT, ND, ND);
}

// Round 20
// 120.971 us; speedup vs baseline: 1.2661x; 1.0390x over previous
//
#include <hip/hip_runtime.h>
#include <hip/hip_bf16.h>
#include <stdint.h>

// Problem constants (from reference)
#define NB 8
#define NT 2048
#define ND 512
#define NH 4
#define NDK 128
#define QV_LD 1024    // row stride of qvb (Q cols 0..511, V cols 512..1023)
#define KW 11
#define C1F 0.12751741567f   /* (1/sqrt(128)) * log2(e), folded into stored Q */

typedef unsigned short u16;
typedef __attribute__((ext_vector_type(4))) float f32x4;
typedef __attribute__((ext_vector_type(16))) float f32x16;
typedef __attribute__((ext_vector_type(4))) float fv4;
typedef __attribute__((ext_vector_type(8))) short s16x8;   // 8 bf16 = 4 VGPR
typedef __attribute__((ext_vector_type(4))) unsigned short u16x4;
typedef __attribute__((ext_vector_type(4))) int i32x4;

#define AS1 __attribute__((address_space(1)))
#define AS3 __attribute__((address_space(3)))

__device__ __forceinline__ u16 f2bf(float f){
  unsigned u = __float_as_uint(f);
  u += 0x7fffu + ((u >> 16) & 1u);      // RNE
  return (u16)(u >> 16);
}
__device__ __forceinline__ float bf2f(u16 h){ return __uint_as_float(((unsigned)h) << 16); }
__device__ __forceinline__ unsigned pack2bf(float a, float b){
  float2 t; t.x = a; t.y = b;
  __hip_bfloat162 h = __float22bfloat162_rn(t);
  return *reinterpret_cast<unsigned*>(&h);
}

// ---------------------------------------------------------------- fused prep:
// blocks [0,1024): x -> bf16 (grid-stride)
// blocks [1024,1792): Wqkv transpose+cvt; [1792,2048): Wout transpose+cvt
// blocks [2048,2056): per-batch mask scan -> pos16 map (0xFFFF = masked), count
__device__ __forceinline__ void transpose_body(
    const float* __restrict__ in, u16* __restrict__ out, int R, int C,
    int bx, int by, int tid)
{
  __shared__ float tile[32][33];
  const int cb = bx * 32, rb = by * 32;
  const int tx = tid & 31, ty = tid >> 5;   // (32,8)
  #pragma unroll
  for (int i = 0; i < 4; ++i)
    tile[ty + i*8][tx] = in[(size_t)(rb + ty + i*8) * C + cb + tx];
  __syncthreads();
  #pragma unroll
  for (int i = 0; i < 4; ++i)
    out[(size_t)(cb + ty + i*8) * R + rb + tx] = f2bf(tile[tx][ty + i*8]);
}

__global__ void prep_kernel(const float* __restrict__ x, u16* __restrict__ xb,
                            const float* __restrict__ Wqkv, u16* __restrict__ wqkvT,
                            const float* __restrict__ Wout, u16* __restrict__ woutT,
                            const float* __restrict__ mask, u16* __restrict__ pos16,
                            int* __restrict__ cntb)
{
  const int bid = blockIdx.x, tid = threadIdx.x;
  if (bid < 1024){
    const int n4 = (NB*NT*ND)/4;
    for (int i = bid*256 + tid; i < n4; i += 1024*256){
      float4 v = reinterpret_cast<const float4*>(x)[i];
      u16x4 o = { f2bf(v.x), f2bf(v.y), f2bf(v.z), f2bf(v.w) };
      reinterpret_cast<u16x4*>(xb)[i] = o;
    }
  } else if (bid < 1792){
    const int idx = bid - 1024;              // grid (48,16)
    transpose_body(Wqkv, wqkvT, 512, 1536, idx % 48, idx / 48, tid);
  } else if (bid < 2048){
    const int idx = bid - 1792;              // grid (16,16)
    transpose_body(Wout, woutT, 512, 512, idx % 16, idx / 16, tid);
  } else {
    // per-batch mask scan -> pos16 (compact position or 0xFFFF), count
    const int b = bid - 2048;
    __shared__ int s[256];
    const float* mb = mask + (size_t)b * NT;
    float4 a = *reinterpret_cast<const float4*>(&mb[tid*8]);
    float4 c4 = *reinterpret_cast<const float4*>(&mb[tid*8 + 4]);
    float vals[8] = {a.x, a.y, a.z, a.w, c4.x, c4.y, c4.z, c4.w};
    int lc = 0;
    #pragma unroll
    for (int j = 0; j < 8; ++j) lc += (vals[j] != 0.f);
    s[tid] = lc; __syncthreads();
    #pragma unroll
    for (int d = 1; d < 256; d <<= 1){
      const int v = (tid >= d) ? s[tid - d] : 0;
      __syncthreads();
      s[tid] += v;
      __syncthreads();
    }
    const int excl = s[tid] - lc;
    u16* pb = pos16 + (size_t)b * NT;
    int off = excl;
    #pragma unroll
    for (int j = 0; j < 8; ++j){
      const int t = tid*8 + j;
      if (vals[j] != 0.f){ pb[t] = (u16)off; ++off; }
      else pb[t] = (u16)0xFFFF;
    }
    if (tid == 0) cntb[b] = s[255];
  }
}

// ---------------------------------------------------------------- QKV GEMM, fused compaction
// BK=64 + XOR swizzle (rule #21, verified R13). XCD-bijective block remap (T1): the 12
// n-blocks sharing an A m-panel land on ONE XCD's L2 (R19 profile: FETCH 71MB = A
// re-fetched ~4x from HBM under default round-robin). nwg=1536 %8==0 -> bijective.
// Per-block column range (block-uniform):
//   n0 <  512 : Q -> qvb[row][gc], PRE-SCALED by C1F (softmax exp2 arg folded in)
//   n0 < 1024 : K -> kcb[bh][pos][dk]  (predicated scatter; pos from pos16)
//   else      : V -> qvb[row][gc-512]  AND  vtc subtiled (predicated scatter)
// Unwritten kcb/vtc tail rows (pos >= cnt) stay garbage: finite, zeroed by attn's
// last-tile predicate -> exact.
__global__ __launch_bounds__(256, 2) void gemm_qkv(
    const u16* __restrict__ A, const u16* __restrict__ Bt, const float* __restrict__ bias,
    const u16* __restrict__ pos16, u16* __restrict__ qvb, u16* __restrict__ kcb,
    u16* __restrict__ vtc)
{
  const int Kd = ND;
  __shared__ u16 As[128 * 64];
  __shared__ u16 Bs[128 * 64];
  const int tid = threadIdx.x;

  // XCD-bijective remap (nwg = 12*128 = 1536, %8 == 0)
  const int lin = blockIdx.x + blockIdx.y * gridDim.x;
  const int nper = (gridDim.x * gridDim.y) >> 3;
  const int wg = (lin & 7) * nper + (lin >> 3);
  const int m0 = (wg / gridDim.x) * 128, n0 = (wg % gridDim.x) * 128;

  const int w = tid >> 6, l = tid & 63, wr = w >> 1, wc = w & 1;
  const int r15 = l & 15, g = l >> 4;

  f32x4 acc[4][4] = {};

  const int r0 = tid >> 3;
  const int scol8 = ((tid & 7) ^ (r0 & 7)) << 3;
  const u16* Ag = A  + (size_t)(m0 + r0) * Kd + scol8;
  const u16* Bg = Bt + (size_t)(n0 + r0) * Kd + scol8;
  u16* Al = &As[(size_t)tid * 8];
  u16* Bl = &Bs[(size_t)tid * 8];

  for (int k0 = 0; k0 < Kd; k0 += 64){
    #pragma unroll
    for (int i = 0; i < 4; ++i)
      __builtin_amdgcn_global_load_lds((AS1 void*)(Ag + (size_t)(i*32) * Kd + k0),
                                       (AS3 void*)(Al + i*2048), 16, 0, 0);
    #pragma unroll
    for (int i = 0; i < 4; ++i)
      __builtin_amdgcn_global_load_lds((AS1 void*)(Bg + (size_t)(i*32) * Kd + k0),
                                       (AS3 void*)(Bl + i*2048), 16, 0, 0);
    __syncthreads();
    #pragma unroll
    for (int kk = 0; kk < 2; ++kk){
      s16x8 af[4], bfr[4];
      #pragma unroll
      for (int m = 0; m < 4; ++m){
        const int R = wr*64 + m*16 + r15;
        af[m] = *reinterpret_cast<const s16x8*>(&As[R*64 + (((kk*4 + g) ^ (r15 & 7)) << 3)]);
      }
      #pragma unroll
      for (int n = 0; n < 4; ++n){
        const int R = wc*64 + n*16 + r15;
        bfr[n] = *reinterpret_cast<const s16x8*>(&Bs[R*64 + (((kk*4 + g) ^ (r15 & 7)) << 3)]);
      }
      #pragma unroll
      for (int m = 0; m < 4; ++m){
        #pragma unroll
        for (int n = 0; n < 4; ++n)
          acc[m][n] = __builtin_amdgcn_mfma_f32_16x16x32_bf16(af[m], bfr[n], acc[m][n], 0, 0, 0);
      }
    }
    __syncthreads();
  }

  const int range = n0 >> 9;                 // 0=Q, 1=K, 2=V (block-uniform)
  const int bb = m0 >> 11;
  const u16* pb = pos16 + (size_t)bb * NT;
  #pragma unroll
  for (int m = 0; m < 4; ++m){
    const int gr0 = m0 + wr*64 + m*16 + g*4;
    const int tm = gr0 & 2047;
    int pos[4];
    if (range != 0){
      #pragma unroll
      for (int j = 0; j < 4; ++j) pos[j] = (int)pb[tm + j];
    }
    #pragma unroll
    for (int n = 0; n < 4; ++n){
      const int gc = n0 + wc*64 + n*16 + r15;
      const float bv = bias[gc];
      if (range == 0){
        #pragma unroll
        for (int j = 0; j < 4; ++j)
          qvb[(size_t)(gr0 + j) * QV_LD + gc] = f2bf((acc[m][n][j] + bv) * C1F);
      } else if (range == 1){
        const int d = gc - 512, bh = bb*4 + (d >> 7), dk = d & 127;
        #pragma unroll
        for (int j = 0; j < 4; ++j){
          if (pos[j] != 0xFFFF)
            kcb[((size_t)bh*NT + pos[j])*NDK + dk] = f2bf(acc[m][n][j] + bv);
        }
      } else {
        const int d = gc - 1024, bh = bb*4 + (d >> 7), dk = d & 127;
        #pragma unroll
        for (int j = 0; j < 4; ++j){
          const u16 hv = f2bf(acc[m][n][j] + bv);
          qvb[(size_t)(gr0 + j) * QV_LD + 512 + d] = hv;
          const int p = pos[j];
          if (p != 0xFFFF)
            vtc[((size_t)bh*32 + (p >> 6))*8192 + ((p & 63) >> 3)*1024 + dk*8 + (p & 7)] = hv;
        }
      }
    }
  }
}

// ---------------------------------------------------------------- out GEMM + fused FSMN
// BK=64 + XOR swizzle + XCD-bijective remap (nwg=512 %8==0). FSMN taps read qvb's V
// half (stride 1024), mask-float zeroing (R8/R16-proven). OOB taps zeroed via mk=0.
__global__ __launch_bounds__(256, 2) void gemm_out(
    const u16* __restrict__ A, const u16* __restrict__ Bt, const float* __restrict__ bias,
    float* __restrict__ Cf, const u16* __restrict__ qvb, const float* __restrict__ mask,
    const float* __restrict__ fsmn_w, int M, int N, int Kd)
{
  __shared__ u16 As[128 * 64];
  __shared__ u16 Bs[128 * 64];
  const int tid = threadIdx.x;

  // XCD-bijective remap (nwg = 4*128 = 512, %8 == 0)
  const int lin = blockIdx.x + blockIdx.y * gridDim.x;
  const int nper = (gridDim.x * gridDim.y) >> 3;
  const int wg = (lin & 7) * nper + (lin >> 3);
  const int m0 = (wg / gridDim.x) * 128, n0 = (wg % gridDim.x) * 128;

  const int w = tid >> 6, l = tid & 63, wr = w >> 1, wc = w & 1;
  const int r15 = l & 15, g = l >> 4;

  f32x4 acc[4][4] = {};

  const int r0 = tid >> 3;
  const int scol8 = ((tid & 7) ^ (r0 & 7)) << 3;
  const u16* Ag = A  + (size_t)(m0 + r0) * Kd + scol8;
  const u16* Bg = Bt + (size_t)(n0 + r0) * Kd + scol8;
  u16* Al = &As[(size_t)tid * 8];
  u16* Bl = &Bs[(size_t)tid * 8];

  for (int k0 = 0; k0 < Kd; k0 += 64){
    #pragma unroll
    for (int i = 0; i < 4; ++i)
      __builtin_amdgcn_global_load_lds((AS1 void*)(Ag + (size_t)(i*32) * Kd + k0),
                                       (AS3 void*)(Al + i*2048), 16, 0, 0);
    #pragma unroll
    for (int i = 0; i < 4; ++i)
      __builtin_amdgcn_global_load_lds((AS1 void*)(Bg + (size_t)(i*32) * Kd + k0),
                                       (AS3 void*)(Bl + i*2048), 16, 0, 0);
    __syncthreads();
    #pragma unroll
    for (int kk = 0; kk < 2; ++kk){
      s16x8 af[4], bfr[4];
      #pragma unroll
      for (int m = 0; m < 4; ++m){
        const int R = wr*64 + m*16 + r15;
        af[m] = *reinterpret_cast<const s16x8*>(&As[R*64 + (((kk*4 + g) ^ (r15 & 7)) << 3)]);
      }
      #pragma unroll
      for (int n = 0; n < 4; ++n){
        const int R = wc*64 + n*16 + r15;
        bfr[n] = *reinterpret_cast<const s16x8*>(&Bs[R*64 + (((kk*4 + g) ^ (r15 & 7)) << 3)]);
      }
      #pragma unroll
      for (int m = 0; m < 4; ++m){
        #pragma unroll
        for (int n = 0; n < 4; ++n)
          acc[m][n] = __builtin_amdgcn_mfma_f32_16x16x32_bf16(af[m], bfr[n], acc[m][n], 0, 0, 0);
      }
    }
    __syncthreads();
  }

  float wv[4][KW];
  #pragma unroll
  for (int n = 0; n < 4; ++n){
    const int gc = n0 + wc*64 + n*16 + r15;
    #pragma unroll
    for (int i = 0; i < KW; ++i) wv[n][i] = fsmn_w[gc*KW + i];
  }
  #pragma unroll
  for (int m = 0; m < 4; ++m){
    const int gr0 = m0 + wr*64 + m*16 + g*4;
    const int bb = gr0 >> 11, t0 = gr0 & 2047;
    const float* mb = mask + (size_t)bb * NT;
    float mk[14];
    #pragma unroll
    for (int i = 0; i < 14; ++i){
      const int tau = t0 - 5 + i;
      mk[i] = ((unsigned)tau < (unsigned)NT) ? mb[tau] : 0.f;
    }
    #pragma unroll
    for (int n = 0; n < 4; ++n){
      const int gc = n0 + wc*64 + n*16 + r15;
      const float bv = bias[gc];
      const u16* vb = qvb + (size_t)bb * NT * QV_LD + 512 + gc;
      float vmv[14];
      #pragma unroll
      for (int i = 0; i < 14; ++i){
        const ptrdiff_t tau = t0 - 5 + i;
        vmv[i] = mk[i] * bf2f(vb[tau * QV_LD]);   // mk=0 zeroes OOB taps
      }
      #pragma unroll
      for (int j = 0; j < 4; ++j){
        float conv = vmv[5 + j];                    // vm[t] residual term
        #pragma unroll
        for (int i = 0; i < KW; ++i) conv = fmaf(wv[n][i], vmv[j + i], conv);
        Cf[(size_t)(gr0 + j) * N + gc] = acc[m][n][j] + bv + mk[5 + j] * conv;
      }
    }
  }
}

// ---------------------------------------------------------------- flash attention, COMPACTED KEYS
// R19 structure (verified): no-max softmax (Q pre-scaled by C1F, p = v_exp(d) directly;
// shift-invariant, |d| tiny vs f32 exp2 range); lrun lane-local; compacted keys
// (~50% of 2048), ntiles runtime, last tile kidx<cnt predicate; K rows 256B compact,
// V subtiled (conflict-free). DO NOT raise launch_bounds 2nd arg (R9 spill lesson).
#define ATT_MFMA(a, bb, c) __builtin_amdgcn_mfma_f32_32x32x16_bf16(a, bb, c, 0, 0, 0)

__global__ __launch_bounds__(256, 2) void attn_kernel(
    const u16* __restrict__ qvb, const u16* __restrict__ kcb,
    const u16* __restrict__ vtc, const int* __restrict__ cntb,
    u16* __restrict__ ctxb)
{
  __shared__ u16 Ks[2][64 * 128];   // [key][dk], swizzled 16B chunks
  __shared__ u16 Vs[2][8 * 128 * 8];// [kg][dk][8 keys] subtiled (linear image of vtc tile)
  const int tid = threadIdx.x;
  const int w = tid >> 6, l = tid & 63, l31 = l & 31, hi = l >> 5;

  // XCD-bijective remap: all 16 q-blocks of one bh land on one XCD (K/V L2 locality)
  const int lin = blockIdx.x + blockIdx.y * 8;    // grid = (8, 64)
  const int xcd = lin & 7, jj = lin >> 3;         // jj 0..63
  const int bh = xcd * 4 + (jj & 3), qblk = jj >> 2;
  const int b = bh >> 2, h = bh & 3;
  const int q0 = qblk * 128;

  const u16* kb   = kcb + (size_t)bh * NT * NDK;
  const u16* vtb  = vtc + (size_t)bh * 32 * 8192;
  const int total = cntb[b];
  const int ntiles = (total + 63) >> 6;

  // Q in registers (B-operand): lane holds Q[q0+w*32+l31][s*16 + hi*8 .. +7]
  s16x8 qf[8];
  {
    const u16* qrow = qvb + (size_t)(b*NT + q0 + w*32 + l31) * QV_LD + h * NDK;
    #pragma unroll
    for (int s = 0; s < 8; ++s)
      qf[s] = *reinterpret_cast<const s16x8*>(qrow + s*16 + hi*8);
  }

  float lrun = 0.f;                 // lane-local; cross-half summed in epilogue
  f32x16 o0 = {}, o1 = {}, o2 = {}, o3 = {};

#define STAGE(buf, kvo) do { \
    _Pragma("unroll") \
    for (int i_ = 0; i_ < 4; ++i_){ \
      const int n_ = i_*256 + tid, kr_ = n_ >> 4, c_ = n_ & 15; \
      const u16* gp_ = kb + (size_t)((kvo) + kr_) * NDK + ((c_ ^ (kr_ & 7)) << 3); \
      __builtin_amdgcn_global_load_lds((AS1 void*)gp_, (AS3 void*)&Ks[buf][n_*8], 16, 0, 0); \
    } \
    const u16* vsrc_ = vtb + ((kvo) >> 6) * 8192; \
    _Pragma("unroll") \
    for (int i_ = 0; i_ < 4; ++i_){ \
      const int n_ = i_*256 + tid; \
      __builtin_amdgcn_global_load_lds((AS1 void*)(vsrc_ + n_*8), \
                                       (AS3 void*)&Vs[buf][n_*8], 16, 0, 0); \
    } \
  } while(0)

  if (ntiles > 0) STAGE(0, 0);
  __syncthreads();
  int cur = 0;

  for (int t = 0; t < ntiles; ++t){
    const int kv0 = t * 64;
    if (t + 1 < ntiles) STAGE(cur ^ 1, kv0 + 64);

    // S^T = K Q^T: d0 keys kv0+0..31, d1 keys kv0+32..63; lane owns q-col l31
    f32x16 d0 = {}, d1 = {};
    __builtin_amdgcn_s_setprio(1);
    #pragma unroll
    for (int s = 0; s < 8; ++s){
      const int cg = s*2 + hi;
      s16x8 kf0 = *reinterpret_cast<const s16x8*>(
          &Ks[cur][ l31*128      + ((cg ^ (l31 & 7)) << 3) ]);
      s16x8 kf1 = *reinterpret_cast<const s16x8*>(
          &Ks[cur][ (32+l31)*128 + ((cg ^ (l31 & 7)) << 3) ]);
      d0 = ATT_MFMA(kf0, qf[s], d0);
      d1 = ATT_MFMA(kf1, qf[s], d1);
    }
    __builtin_amdgcn_s_setprio(0);

    // p = exp2(d) directly; last tile: kidx<cnt predicate zeroes garbage keys
    float ts = 0.f;
    if (t + 1 < ntiles){
      #pragma unroll
      for (int r = 0; r < 16; ++r){
        const float p0 = __builtin_amdgcn_exp2f(d0[r]);
        const float p1 = __builtin_amdgcn_exp2f(d1[r]);
        d0[r] = p0; d1[r] = p1; ts += p0 + p1;
      }
    } else {
      #pragma unroll
      for (int r = 0; r < 16; ++r){
        const int kidx = kv0 + (r >> 2)*8 + 4*hi + (r & 3);
        const float p0 = (kidx      < total) ? __builtin_amdgcn_exp2f(d0[r]) : 0.f;
        const float p1 = (kidx + 32 < total) ? __builtin_amdgcn_exp2f(d1[r]) : 0.f;
        d0[r] = p0; d1[r] = p1; ts += p0 + p1;
      }
    }
    lrun += ts;

    // pack p -> bf16 pairs
    unsigned pku[2][4][2];
    #pragma unroll
    for (int r8 = 0; r8 < 4; ++r8){
      pku[0][r8][0] = pack2bf(d0[4*r8+0], d0[4*r8+1]);
      pku[0][r8][1] = pack2bf(d0[4*r8+2], d0[4*r8+3]);
      pku[1][r8][0] = pack2bf(d1[4*r8+0], d1[4*r8+1]);
      pku[1][r8][1] = pack2bf(d1[4*r8+2], d1[4*r8+3]);
    }

    // PV: per k-step build A-frag with 2 permlane32_swap, then 4 dk-blocks.
    const int vb0 = hi*1024 + l31*8;
    #pragma unroll
    for (int ks = 0; ks < 4; ++ks){
      const int bb = ks >> 1, rlo = (ks & 1) * 2;
      int u0 = (int)pku[bb][rlo][0],   u1 = (int)pku[bb][rlo][1];
      int v0 = (int)pku[bb][rlo+1][0], v1 = (int)pku[bb][rlo+1][1];
      asm("v_permlane32_swap_b32 %0, %1" : "+v"(u0), "+v"(v0));
      asm("v_permlane32_swap_b32 %0, %1" : "+v"(u1), "+v"(v1));
      union { i32x4 i; s16x8 hv; } pu;
      pu.i[0] = u0; pu.i[1] = u1; pu.i[2] = v0; pu.i[3] = v1;
      const int off = ks*2048 + vb0;
      s16x8 vf0 = *reinterpret_cast<const s16x8*>(&Vs[cur][ off       ]);
      s16x8 vf1 = *reinterpret_cast<const s16x8*>(&Vs[cur][ off + 256 ]);
      s16x8 vf2 = *reinterpret_cast<const s16x8*>(&Vs[cur][ off + 512 ]);
      s16x8 vf3 = *reinterpret_cast<const s16x8*>(&Vs[cur][ off + 768 ]);
      __builtin_amdgcn_s_setprio(1);
      o0 = ATT_MFMA(pu.hv, vf0, o0);
      o1 = ATT_MFMA(pu.hv, vf1, o1);
      o2 = ATT_MFMA(pu.hv, vf2, o2);
      o3 = ATT_MFMA(pu.hv, vf3, o3);
      __builtin_amdgcn_s_setprio(0);
    }

    __syncthreads();
    cur ^= 1;
  }

  // epilogue: cross-half l sum once; O rows q = (r&3)+8*(r>>2)+4*hi, col dk = blk*32+l31
  const float lsum = lrun + __shfl_xor(lrun, 32);
  #pragma unroll
  for (int r = 0; r < 16; ++r){
    const int qs = (r & 3) + 8*(r >> 2) + 4*hi;
    const float lr = __shfl(lsum, qs);
    const float rl = (lr > 0.f) ? (1.f / lr) : 0.f;
    const int row = q0 + w*32 + qs;
    u16* cp = ctxb + (size_t)(b*NT + row) * ND + h*NDK + l31;
    cp[0]  = f2bf(o0[r] * rl);
    cp[32] = f2bf(o1[r] * rl);
    cp[64] = f2bf(o2[r] * rl);
    cp[96] = f2bf(o3[r] * rl);
  }
#undef STAGE
}

// ---------------------------------------------------------------- launcher
extern "C" void kernel_launch(void* const* d_in, const int* in_sizes, int n_in,
                              void* d_out, int out_size, void* d_ws, size_t ws_size,
                              hipStream_t stream) {
  const float* x      = (const float*)d_in[0];
  const float* mask   = (const float*)d_in[1];
  const float* Wqkv   = (const float*)d_in[2];
  const float* bqkv   = (const float*)d_in[3];
  const float* Wout   = (const float*)d_in[4];
  const float* bout   = (const float*)d_in[5];
  const float* fsmn_w = (const float*)d_in[6];
  float* out = (float*)d_out;

  // workspace layout (bytes), total ~103 MB
  char* ws = (char*)d_ws;
  u16* xb    = (u16*)ws;                         // 16,777,216
  u16* wqkvT = (u16*)(ws + 16777216);            //  1,572,864
  u16* woutT = (u16*)(ws + 18350080);            //    524,288
  u16* qvb   = (u16*)(ws + 18874368);            // 33,554,432  (16384 x 1024 bf16)
  u16* kcb   = (u16*)(ws + 52428800);            // 16,777,216
  u16* vtc   = (u16*)(ws + 69206016);            // 16,777,216
  u16* ctxb  = (u16*)(ws + 85983232);            // 16,777,216
  u16* pos16 = (u16*)(ws + 102760448);           //     32,768
  int* cntb  = (int*)(ws + 102793216);           //         32

  prep_kernel<<<2056, 256, 0, stream>>>(x, xb, Wqkv, wqkvT, Wout, woutT,
                                        mask, pos16, cntb);
  gemm_qkv<<<dim3(1536/128, 16384/128), 256, 0, stream>>>(
      xb, wqkvT, bqkv, pos16, qvb, kcb, vtc);
  attn_kernel<<<dim3(8, 64), 256, 0, stream>>>(qvb, kcb, vtc, cntb, ctxb);
  gemm_out<<<dim3(512/128, 16384/128), 256, 0, stream>>>(
      ctxb, woutT, bout, out, qvb, mask, fsmn_w, NB*NT, ND, ND);
}

// Round 21
// 119.117 us; speedup vs baseline: 1.2858x; 1.0156x over previous
//
#include <hip/hip_runtime.h>
#include <hip/hip_bf16.h>
#include <stdint.h>

// Problem constants (from reference)
#define NB 8
#define NT 2048
#define ND 512
#define NH 4
#define NDK 128
#define QKV_LD 1536   // qkvb row stride: Q 0..511, K 512..1023, V 1024..1535
#define KW 11
#define C1F 0.12751741567f   /* (1/sqrt(128)) * log2(e); folded into Wq/bq */

typedef unsigned short u16;
typedef __attribute__((ext_vector_type(4))) float f32x4;
typedef __attribute__((ext_vector_type(16))) float f32x16;
typedef __attribute__((ext_vector_type(4))) float fv4;
typedef __attribute__((ext_vector_type(8))) short s16x8;   // 8 bf16 = 4 VGPR
typedef __attribute__((ext_vector_type(4))) unsigned short u16x4;
typedef __attribute__((ext_vector_type(4))) int i32x4;

#define AS1 __attribute__((address_space(1)))
#define AS3 __attribute__((address_space(3)))

__device__ __forceinline__ u16 f2bf(float f){
  unsigned u = __float_as_uint(f);
  u += 0x7fffu + ((u >> 16) & 1u);      // RNE
  return (u16)(u >> 16);
}
__device__ __forceinline__ float bf2f(u16 h){ return __uint_as_float(((unsigned)h) << 16); }
__device__ __forceinline__ unsigned pack2bf(float a, float b){
  float2 t; t.x = a; t.y = b;
  __hip_bfloat162 h = __float22bfloat162_rn(t);
  return *reinterpret_cast<unsigned*>(&h);
}

// ---------------------------------------------------------------- fused prep:
// blocks [0,1024): x -> bf16 (grid-stride)
// blocks [1024,1792): Wqkv transpose+cvt (Q rows scaled by C1F); [1792,2048): Wout
// blocks [2048,2056): per-batch mask scan -> compact key index list (64-pad) + count
__device__ __forceinline__ void transpose_body(
    const float* __restrict__ in, u16* __restrict__ out, int R, int C,
    int bx, int by, int tid, float sc)
{
  __shared__ float tile[32][33];
  const int cb = bx * 32, rb = by * 32;
  const int tx = tid & 31, ty = tid >> 5;   // (32,8)
  #pragma unroll
  for (int i = 0; i < 4; ++i)
    tile[ty + i*8][tx] = in[(size_t)(rb + ty + i*8) * C + cb + tx];
  __syncthreads();
  #pragma unroll
  for (int i = 0; i < 4; ++i)
    out[(size_t)(cb + ty + i*8) * R + rb + tx] = f2bf(tile[tx][ty + i*8] * sc);
}

__global__ void prep_kernel(const float* __restrict__ x, u16* __restrict__ xb,
                            const float* __restrict__ Wqkv, u16* __restrict__ wqkvT,
                            const float* __restrict__ Wout, u16* __restrict__ woutT,
                            const float* __restrict__ mask, u16* __restrict__ idxb,
                            int* __restrict__ cntb)
{
  const int bid = blockIdx.x, tid = threadIdx.x;
  if (bid < 1024){
    const int n4 = (NB*NT*ND)/4;
    for (int i = bid*256 + tid; i < n4; i += 1024*256){
      float4 v = reinterpret_cast<const float4*>(x)[i];
      u16x4 o = { f2bf(v.x), f2bf(v.y), f2bf(v.z), f2bf(v.w) };
      reinterpret_cast<u16x4*>(xb)[i] = o;
    }
  } else if (bid < 1792){
    const int idx = bid - 1024;              // grid (48,16); cols < 512 are Q -> xC1F
    const int bx = idx % 48;
    const float sc = (bx < 16) ? C1F : 1.0f; // block-uniform (cb = bx*32)
    transpose_body(Wqkv, wqkvT, 512, 1536, bx, idx / 48, tid, sc);
  } else if (bid < 2048){
    const int idx = bid - 1792;              // grid (16,16)
    transpose_body(Wout, woutT, 512, 512, idx % 16, idx / 16, tid, 1.0f);
  } else {
    // per-batch mask scan: ascending valid-key list (64-padded with 0), count
    const int b = bid - 2048;
    __shared__ int s[256];
    const float* mb = mask + (size_t)b * NT;
    float4 a = *reinterpret_cast<const float4*>(&mb[tid*8]);
    float4 c4 = *reinterpret_cast<const float4*>(&mb[tid*8 + 4]);
    float vals[8] = {a.x, a.y, a.z, a.w, c4.x, c4.y, c4.z, c4.w};
    int lc = 0;
    #pragma unroll
    for (int j = 0; j < 8; ++j) lc += (vals[j] != 0.f);
    s[tid] = lc; __syncthreads();
    #pragma unroll
    for (int d = 1; d < 256; d <<= 1){
      const int v = (tid >= d) ? s[tid - d] : 0;
      __syncthreads();
      s[tid] += v;
      __syncthreads();
    }
    const int excl = s[tid] - lc;
    const int total = s[255];
    u16* ib = idxb + (size_t)b * NT;
    int off = excl;
    #pragma unroll
    for (int j = 0; j < 8; ++j)
      if (vals[j] != 0.f) ib[off++] = (u16)(tid*8 + j);
    const int padded = (total + 63) & ~63;
    for (int j = total + tid; j < padded; j += 256) ib[j] = 0;
    if (tid == 0) cntb[b] = total;
  }
}

// ---------------------------------------------------------------- KV compaction (R16-proven)
// Per (batch, 64-key compact tile): gather K rows -> kcb[bh][j][128] (plain rows) and
// V -> vtc[bh][tile][kg][dk][8] (subtiled 16B chunks) via LDS transpose.
__global__ __launch_bounds__(256) void kv_compact(
    const u16* __restrict__ qkvb, const u16* __restrict__ idxb,
    const int* __restrict__ cntb, u16* __restrict__ kcb, u16* __restrict__ vtc)
{
  const int b = blockIdx.y, tile = blockIdx.x, tid = threadIdx.x;
  const int total = cntb[b];
  if (tile * 64 >= ((total + 63) & ~63)) return;
  __shared__ u16 idx64[64];
  __shared__ u16 vbuf[64 * 128];
  if (tid < 64) idx64[tid] = idxb[(size_t)b * NT + tile*64 + tid];
  __syncthreads();
  #pragma unroll
  for (int h = 0; h < 4; ++h){
    // K: 1024 x 16B chunks, contiguous row copies
    #pragma unroll
    for (int i = 0; i < 4; ++i){
      const int c = i*256 + tid, key = c >> 4, ck = c & 15;
      const int srcT = idx64[key];
      const u16* sp = qkvb + ((size_t)b*NT + srcT)*QKV_LD + ND + h*NDK + ck*8;
      u16* dp = kcb + ((size_t)(b*4+h)*NT + tile*64 + key)*NDK + ck*8;
      *reinterpret_cast<s16x8*>(dp) = *reinterpret_cast<const s16x8*>(sp);
    }
    // V: stage rows -> LDS, then write subtiled [kg][dk][8keys]
    #pragma unroll
    for (int i = 0; i < 4; ++i){
      const int c = i*256 + tid, key = c >> 4, ck = c & 15;
      const int srcT = idx64[key];
      const u16* sp = qkvb + ((size_t)b*NT + srcT)*QKV_LD + 2*ND + h*NDK + ck*8;
      *reinterpret_cast<s16x8*>(&vbuf[key*128 + ck*8]) =
          *reinterpret_cast<const s16x8*>(sp);
    }
    __syncthreads();
    u16* vt = vtc + ((size_t)(b*4+h)*32 + tile) * 8192;
    #pragma unroll
    for (int i = 0; i < 4; ++i){
      const int c = i*256 + tid, kg = c >> 7, dk = c & 127;
      s16x8 ov;
      #pragma unroll
      for (int e = 0; e < 8; ++e) ov[e] = (short)vbuf[(kg*8 + e)*128 + dk];
      *reinterpret_cast<s16x8*>(&vt[c*8]) = ov;
    }
    __syncthreads();
  }
}

// ---------------------------------------------------------------- bf16 GEMM  C = A * Bt^T + bias
// BK=64 + XOR swizzle (rule #21, verified R13) + XCD-bijective remap (T1; nwg %8 == 0).
// EPI==0: C -> bf16 qkvb; bias scaled by C1F for Q cols (weights pre-scaled in prep).
// EPI==1: C -> f32 out with FUSED FSMN epilogue (taps from qkvb V cols, mask-float).
template<int EPI>
__global__ __launch_bounds__(256, 2) void gemm_bt(
    const u16* __restrict__ A, const u16* __restrict__ Bt, const float* __restrict__ bias,
    u16* __restrict__ Cb, float* __restrict__ Cf,
    const u16* __restrict__ qkvb, const float* __restrict__ mask,
    const float* __restrict__ fsmn_w,
    int M, int N, int Kd)
{
  __shared__ u16 As[128 * 64];
  __shared__ u16 Bs[128 * 64];
  const int tid = threadIdx.x;

  // XCD-bijective remap (nwg = 1536 or 512, both %8 == 0)
  const int lin = blockIdx.x + blockIdx.y * gridDim.x;
  const int nper = (gridDim.x * gridDim.y) >> 3;
  const int wg = (lin & 7) * nper + (lin >> 3);
  const int m0 = (wg / gridDim.x) * 128, n0 = (wg % gridDim.x) * 128;

  const int w = tid >> 6, l = tid & 63, wr = w >> 1, wc = w & 1;
  const int r15 = l & 15, g = l >> 4;

  f32x4 acc[4][4] = {};

  const int r0 = tid >> 3;
  const int scol8 = ((tid & 7) ^ (r0 & 7)) << 3;   // u16 offset within the 64-col row
  const u16* Ag = A  + (size_t)(m0 + r0) * Kd + scol8;
  const u16* Bg = Bt + (size_t)(n0 + r0) * Kd + scol8;
  u16* Al = &As[(size_t)tid * 8];
  u16* Bl = &Bs[(size_t)tid * 8];

  for (int k0 = 0; k0 < Kd; k0 += 64){
    #pragma unroll
    for (int i = 0; i < 4; ++i)
      __builtin_amdgcn_global_load_lds((AS1 void*)(Ag + (size_t)(i*32) * Kd + k0),
                                       (AS3 void*)(Al + i*2048), 16, 0, 0);
    #pragma unroll
    for (int i = 0; i < 4; ++i)
      __builtin_amdgcn_global_load_lds((AS1 void*)(Bg + (size_t)(i*32) * Kd + k0),
                                       (AS3 void*)(Bl + i*2048), 16, 0, 0);
    __syncthreads();
    #pragma unroll
    for (int kk = 0; kk < 2; ++kk){
      s16x8 af[4], bfr[4];
      #pragma unroll
      for (int m = 0; m < 4; ++m){
        const int R = wr*64 + m*16 + r15;
        af[m] = *reinterpret_cast<const s16x8*>(
            &As[R*64 + (((kk*4 + g) ^ (r15 & 7)) << 3)]);
      }
      #pragma unroll
      for (int n = 0; n < 4; ++n){
        const int R = wc*64 + n*16 + r15;
        bfr[n] = *reinterpret_cast<const s16x8*>(
            &Bs[R*64 + (((kk*4 + g) ^ (r15 & 7)) << 3)]);
      }
      #pragma unroll
      for (int m = 0; m < 4; ++m){
        #pragma unroll
        for (int n = 0; n < 4; ++n)
          acc[m][n] = __builtin_amdgcn_mfma_f32_16x16x32_bf16(af[m], bfr[n], acc[m][n], 0, 0, 0);
      }
    }
    __syncthreads();
  }

  if (EPI == 0){
    const float bsc = (n0 < 512) ? C1F : 1.0f;   // block-uniform: Q cols bias scale
    #pragma unroll
    for (int m = 0; m < 4; ++m){
      const int gr0 = m0 + wr*64 + m*16 + g*4;
      #pragma unroll
      for (int n = 0; n < 4; ++n){
        const int gc = n0 + wc*64 + n*16 + r15;
        const float bv = bias[gc] * bsc;
        #pragma unroll
        for (int j = 0; j < 4; ++j)
          Cb[(size_t)(gr0 + j) * N + gc] = f2bf(acc[m][n][j] + bv);
      }
    }
  } else {
    // fused FSMN epilogue (R16-proven): taps from qkvb V cols, mask-float zeroing
    float wv[4][KW];
    #pragma unroll
    for (int n = 0; n < 4; ++n){
      const int gc = n0 + wc*64 + n*16 + r15;
      #pragma unroll
      for (int i = 0; i < KW; ++i) wv[n][i] = fsmn_w[gc*KW + i];
    }
    #pragma unroll
    for (int m = 0; m < 4; ++m){
      const int gr0 = m0 + wr*64 + m*16 + g*4;
      const int bb = gr0 >> 11, t0 = gr0 & 2047;
      const float* mb = mask + (size_t)bb * NT;
      float mk[14];
      #pragma unroll
      for (int i = 0; i < 14; ++i){
        const int tau = t0 - 5 + i;
        mk[i] = ((unsigned)tau < (unsigned)NT) ? mb[tau] : 0.f;
      }
      #pragma unroll
      for (int n = 0; n < 4; ++n){
        const int gc = n0 + wc*64 + n*16 + r15;
        const float bv = bias[gc];
        const u16* vb = qkvb + (size_t)bb * NT * QKV_LD + 2*ND + gc;
        float vmv[14];
        #pragma unroll
        for (int i = 0; i < 14; ++i){
          const ptrdiff_t tau = t0 - 5 + i;
          vmv[i] = mk[i] * bf2f(vb[tau * QKV_LD]);   // mk=0 zeroes OOB taps
        }
        #pragma unroll
        for (int j = 0; j < 4; ++j){
          float conv = vmv[5 + j];                    // vm[t] residual term
          #pragma unroll
          for (int i = 0; i < KW; ++i) conv = fmaf(wv[n][i], vmv[j + i], conv);
          Cf[(size_t)(gr0 + j) * N + gc] = acc[m][n][j] + bv + mk[5 + j] * conv;
        }
      }
    }
  }
}

// ---------------------------------------------------------------- flash attention, COMPACTED KEYS
// R19/R20 structure (no-max softmax: Q pre-scaled by C1F upstream, p = v_exp(d)
// directly; shift-invariant, |d| tiny vs f32 exp2 range; lrun lane-local). Compacted
// keys (~50%); ntiles runtime; last tile kidx<cnt predicate (also zeroes pad-key
// duplicates). K rows 256B compact; V subtiled (conflict-free). Q from qkvb.
// DO NOT raise launch_bounds 2nd arg (R9 spill lesson).
#define ATT_MFMA(a, bb, c) __builtin_amdgcn_mfma_f32_32x32x16_bf16(a, bb, c, 0, 0, 0)

__global__ __launch_bounds__(256, 2) void attn_kernel(
    const u16* __restrict__ qkvb, const u16* __restrict__ kcb,
    const u16* __restrict__ vtc, const int* __restrict__ cntb,
    u16* __restrict__ ctxb)
{
  __shared__ u16 Ks[2][64 * 128];   // [key][dk], swizzled 16B chunks
  __shared__ u16 Vs[2][8 * 128 * 8];// [kg][dk][8 keys] subtiled (linear image of vtc tile)
  const int tid = threadIdx.x;
  const int w = tid >> 6, l = tid & 63, l31 = l & 31, hi = l >> 5;

  // XCD-bijective remap: all 16 q-blocks of one bh land on one XCD (K/V L2 locality)
  const int lin = blockIdx.x + blockIdx.y * 8;    // grid = (8, 64)
  const int xcd = lin & 7, jj = lin >> 3;         // jj 0..63
  const int bh = xcd * 4 + (jj & 3), qblk = jj >> 2;
  const int b = bh >> 2, h = bh & 3;
  const int q0 = qblk * 128;

  const u16* kb   = kcb + (size_t)bh * NT * NDK;
  const u16* vtb  = vtc + (size_t)bh * 32 * 8192;
  const int total = cntb[b];
  const int ntiles = (total + 63) >> 6;

  // Q in registers (B-operand): lane holds Q[q0+w*32+l31][s*16 + hi*8 .. +7]
  s16x8 qf[8];
  {
    const u16* qrow = qkvb + (size_t)(b*NT + q0 + w*32 + l31) * QKV_LD + h * NDK;
    #pragma unroll
    for (int s = 0; s < 8; ++s)
      qf[s] = *reinterpret_cast<const s16x8*>(qrow + s*16 + hi*8);
  }

  float lrun = 0.f;                 // lane-local; cross-half summed in epilogue
  f32x16 o0 = {}, o1 = {}, o2 = {}, o3 = {};

#define STAGE(buf, kvo) do { \
    _Pragma("unroll") \
    for (int i_ = 0; i_ < 4; ++i_){ \
      const int n_ = i_*256 + tid, kr_ = n_ >> 4, c_ = n_ & 15; \
      const u16* gp_ = kb + (size_t)((kvo) + kr_) * NDK + ((c_ ^ (kr_ & 7)) << 3); \
      __builtin_amdgcn_global_load_lds((AS1 void*)gp_, (AS3 void*)&Ks[buf][n_*8], 16, 0, 0); \
    } \
    const u16* vsrc_ = vtb + ((kvo) >> 6) * 8192; \
    _Pragma("unroll") \
    for (int i_ = 0; i_ < 4; ++i_){ \
      const int n_ = i_*256 + tid; \
      __builtin_amdgcn_global_load_lds((AS1 void*)(vsrc_ + n_*8), \
                                       (AS3 void*)&Vs[buf][n_*8], 16, 0, 0); \
    } \
  } while(0)

  if (ntiles > 0) STAGE(0, 0);
  __syncthreads();
  int cur = 0;

  for (int t = 0; t < ntiles; ++t){
    const int kv0 = t * 64;
    if (t + 1 < ntiles) STAGE(cur ^ 1, kv0 + 64);

    // S^T = K Q^T: d0 keys kv0+0..31, d1 keys kv0+32..63; lane owns q-col l31
    f32x16 d0 = {}, d1 = {};
    __builtin_amdgcn_s_setprio(1);
    #pragma unroll
    for (int s = 0; s < 8; ++s){
      const int cg = s*2 + hi;
      s16x8 kf0 = *reinterpret_cast<const s16x8*>(
          &Ks[cur][ l31*128      + ((cg ^ (l31 & 7)) << 3) ]);
      s16x8 kf1 = *reinterpret_cast<const s16x8*>(
          &Ks[cur][ (32+l31)*128 + ((cg ^ (l31 & 7)) << 3) ]);
      d0 = ATT_MFMA(kf0, qf[s], d0);
      d1 = ATT_MFMA(kf1, qf[s], d1);
    }
    __builtin_amdgcn_s_setprio(0);

    // p = exp2(d) directly; last tile: kidx<cnt predicate zeroes garbage/pad keys
    float ts = 0.f;
    if (t + 1 < ntiles){
      #pragma unroll
      for (int r = 0; r < 16; ++r){
        const float p0 = __builtin_amdgcn_exp2f(d0[r]);
        const float p1 = __builtin_amdgcn_exp2f(d1[r]);
        d0[r] = p0; d1[r] = p1; ts += p0 + p1;
      }
    } else {
      #pragma unroll
      for (int r = 0; r < 16; ++r){
        const int kidx = kv0 + (r >> 2)*8 + 4*hi + (r & 3);
        const float p0 = (kidx      < total) ? __builtin_amdgcn_exp2f(d0[r]) : 0.f;
        const float p1 = (kidx + 32 < total) ? __builtin_amdgcn_exp2f(d1[r]) : 0.f;
        d0[r] = p0; d1[r] = p1; ts += p0 + p1;
      }
    }
    lrun += ts;

    // pack p -> bf16 pairs
    unsigned pku[2][4][2];
    #pragma unroll
    for (int r8 = 0; r8 < 4; ++r8){
      pku[0][r8][0] = pack2bf(d0[4*r8+0], d0[4*r8+1]);
      pku[0][r8][1] = pack2bf(d0[4*r8+2], d0[4*r8+3]);
      pku[1][r8][0] = pack2bf(d1[4*r8+0], d1[4*r8+1]);
      pku[1][r8][1] = pack2bf(d1[4*r8+2], d1[4*r8+3]);
    }

    // PV: per k-step build A-frag with 2 permlane32_swap, then 4 dk-blocks.
    const int vb0 = hi*1024 + l31*8;
    #pragma unroll
    for (int ks = 0; ks < 4; ++ks){
      const int bb = ks >> 1, rlo = (ks & 1) * 2;
      int u0 = (int)pku[bb][rlo][0],   u1 = (int)pku[bb][rlo][1];
      int v0 = (int)pku[bb][rlo+1][0], v1 = (int)pku[bb][rlo+1][1];
      asm("v_permlane32_swap_b32 %0, %1" : "+v"(u0), "+v"(v0));
      asm("v_permlane32_swap_b32 %0, %1" : "+v"(u1), "+v"(v1));
      union { i32x4 i; s16x8 hv; } pu;
      pu.i[0] = u0; pu.i[1] = u1; pu.i[2] = v0; pu.i[3] = v1;
      const int off = ks*2048 + vb0;
      s16x8 vf0 = *reinterpret_cast<const s16x8*>(&Vs[cur][ off       ]);
      s16x8 vf1 = *reinterpret_cast<const s16x8*>(&Vs[cur][ off + 256 ]);
      s16x8 vf2 = *reinterpret_cast<const s16x8*>(&Vs[cur][ off + 512 ]);
      s16x8 vf3 = *reinterpret_cast<const s16x8*>(&Vs[cur][ off + 768 ]);
      __builtin_amdgcn_s_setprio(1);
      o0 = ATT_MFMA(pu.hv, vf0, o0);
      o1 = ATT_MFMA(pu.hv, vf1, o1);
      o2 = ATT_MFMA(pu.hv, vf2, o2);
      o3 = ATT_MFMA(pu.hv, vf3, o3);
      __builtin_amdgcn_s_setprio(0);
    }

    __syncthreads();
    cur ^= 1;
  }

  // epilogue: cross-half l sum once; O rows q = (r&3)+8*(r>>2)+4*hi, col dk = blk*32+l31
  const float lsum = lrun + __shfl_xor(lrun, 32);
  #pragma unroll
  for (int r = 0; r < 16; ++r){
    const int qs = (r & 3) + 8*(r >> 2) + 4*hi;
    const float lr = __shfl(lsum, qs);
    const float rl = (lr > 0.f) ? (1.f / lr) : 0.f;
    const int row = q0 + w*32 + qs;
    u16* cp = ctxb + (size_t)(b*NT + row) * ND + h*NDK + l31;
    cp[0]  = f2bf(o0[r] * rl);
    cp[32] = f2bf(o1[r] * rl);
    cp[64] = f2bf(o2[r] * rl);
    cp[96] = f2bf(o3[r] * rl);
  }
#undef STAGE
}

// ---------------------------------------------------------------- launcher
extern "C" void kernel_launch(void* const* d_in, const int* in_sizes, int n_in,
                              void* d_out, int out_size, void* d_ws, size_t ws_size,
                              hipStream_t stream) {
  const float* x      = (const float*)d_in[0];
  const float* mask   = (const float*)d_in[1];
  const float* Wqkv   = (const float*)d_in[2];
  const float* bqkv   = (const float*)d_in[3];
  const float* Wout   = (const float*)d_in[4];
  const float* bout   = (const float*)d_in[5];
  const float* fsmn_w = (const float*)d_in[6];
  float* out = (float*)d_out;

  // workspace layout (bytes), R16-proven ~102.8 MB: kcb reuses xb (dead after gemm0).
  char* ws = (char*)d_ws;
  u16* xb    = (u16*)ws;                         // 16,777,216  (kcb after gemm0)
  u16* kcb   = (u16*)ws;
  u16* wqkvT = (u16*)(ws + 16777216);            //  1,572,864
  u16* woutT = (u16*)(ws + 18350080);            //    524,288
  u16* qkvb  = (u16*)(ws + 18874368);            // 50,331,648
  u16* ctxb  = (u16*)(ws + 69206016);            // 16,777,216
  u16* vtc   = (u16*)(ws + 85983232);            // 16,777,216
  u16* idxb  = (u16*)(ws + 102760448);           //     32,768
  int* cntb  = (int*)(ws + 102793216);           //         32

  prep_kernel<<<2056, 256, 0, stream>>>(x, xb, Wqkv, wqkvT, Wout, woutT,
                                        mask, idxb, cntb);
  gemm_bt<0><<<dim3(1536/128, 16384/128), 256, 0, stream>>>(
      xb, wqkvT, bqkv, qkvb, nullptr, nullptr, nullptr, nullptr, NB*NT, QKV_LD, ND);
  kv_compact<<<dim3(32, 8), 256, 0, stream>>>(qkvb, idxb, cntb, kcb, vtc);
  attn_kernel<<<dim3(8, 64), 256, 0, stream>>>(qkvb, kcb, vtc, cntb, ctxb);
  gemm_bt<1><<<dim3(512/128, 16384/128), 256, 0, stream>>>(
      ctxb, woutT, bout, nullptr, out, qkvb, mask, fsmn_w, NB*NT, ND, ND);
}